// Round 1
// baseline (974.464 us; speedup 1.0000x reference)
//
#include <hip/hip_runtime.h>

#define N_NODES 50000
#define N_EDGES 800000
#define D 128
#define H 16
#define DH 512

typedef __attribute__((ext_vector_type(8))) short short8;
typedef __attribute__((ext_vector_type(4))) float f32x4;

static __device__ __forceinline__ unsigned short f2bf(float f) {
    unsigned u = __float_as_uint(f);
    u += 0x7FFF + ((u >> 16) & 1);   // round-to-nearest-even
    return (unsigned short)(u >> 16);
}

// ---------------- LayerNorm (f32 in -> bf16 out), one wave per row ----------------
__global__ void ln_kernel(const float* __restrict__ x, const float* __restrict__ g,
                          const float* __restrict__ b, unsigned short* __restrict__ out, int n) {
    int w = (blockIdx.x * blockDim.x + threadIdx.x) >> 6;
    int lane = threadIdx.x & 63;
    if (w >= n) return;
    float2 v = *(const float2*)(x + (size_t)w * D + lane * 2);
    float s = v.x + v.y, ss = v.x * v.x + v.y * v.y;
#pragma unroll
    for (int off = 32; off; off >>= 1) { s += __shfl_xor(s, off); ss += __shfl_xor(ss, off); }
    float mean = s * (1.0f / D);
    float var = ss * (1.0f / D) - mean * mean;
    float rstd = rsqrtf(var + 1e-5f);
    float2 gv = *(const float2*)(g + lane * 2);
    float2 bv = *(const float2*)(b + lane * 2);
    ushort2 o;
    o.x = f2bf((v.x - mean) * rstd * gv.x + bv.x);
    o.y = f2bf((v.y - mean) * rstd * gv.y + bv.y);
    *(ushort2*)(out + (size_t)w * D + lane * 2) = o;
}

// ---------------- weight transpose+convert: src[in][out] f32 -> dst[out][in] bf16 ----------------
__global__ void transpose_bf_kernel(const float* __restrict__ src, unsigned short* __restrict__ dst,
                                    int in_dim, int out_dim) {
    int idx = blockIdx.x * blockDim.x + threadIdx.x;
    if (idx >= in_dim * out_dim) return;
    int o = idx / in_dim, i = idx - o * in_dim;
    dst[idx] = f2bf(src[i * out_dim + o]);
}

__global__ void bias_concat_kernel(const float* __restrict__ bq, const float* __restrict__ bk,
                                   const float* __restrict__ bv, const float* __restrict__ bs,
                                   float* __restrict__ out) {
    int i = blockIdx.x * blockDim.x + threadIdx.x;
    if (i >= 512) return;
    const float* p = i < 128 ? bq : i < 256 ? bk : i < 384 ? bv : bs;
    out[i] = p[i & 127];
}

// ---------------- CSR build ----------------
__global__ void hist_kernel(const int* __restrict__ edge_index, int* __restrict__ counts) {
    int e = blockIdx.x * blockDim.x + threadIdx.x;
    if (e < N_EDGES) atomicAdd(&counts[edge_index[N_EDGES + e]], 1);
}

__global__ void scan_kernel(const int* __restrict__ counts, int* __restrict__ row_ptr,
                            int* __restrict__ cursor) {
    __shared__ int sm[1024];
    __shared__ int running;
    int tid = threadIdx.x;
    if (tid == 0) running = 0;
    __syncthreads();
    for (int base = 0; base < N_NODES; base += 1024) {
        int v = (base + tid < N_NODES) ? counts[base + tid] : 0;
        sm[tid] = v;
        __syncthreads();
        for (int off = 1; off < 1024; off <<= 1) {
            int t = (tid >= off) ? sm[tid - off] : 0;
            __syncthreads();
            sm[tid] += t;
            __syncthreads();
        }
        if (base + tid < N_NODES) {
            int excl = running + sm[tid] - v;
            row_ptr[base + tid] = excl;
            cursor[base + tid] = excl;
        }
        __syncthreads();
        if (tid == 0) running += sm[1023];
        __syncthreads();
    }
    if (tid == 0) row_ptr[N_NODES] = running;
}

__global__ void scatter_kernel(const int* __restrict__ edge_index, int* __restrict__ cursor,
                               int* __restrict__ eord) {
    int e = blockIdx.x * blockDim.x + threadIdx.x;
    if (e < N_EDGES) {
        int pos = atomicAdd(&cursor[edge_index[N_EDGES + e]], 1);
        eord[pos] = e;
    }
}

// ---------------- generic bf16 MFMA GEMM: out[M,Nout] = A[M,KD] @ BT[Nout,KD]^T + bias ----------------
enum { EPI_F32 = 0, EPI_RESID = 1, EPI_SILU_BF = 2, EPI_ADDOUT = 3 };

template <int KD, int EPI>
__global__ void gemm_kernel(const unsigned short* __restrict__ A, const unsigned short* __restrict__ BT,
                            const float* __restrict__ bias, void* __restrict__ outp,
                            const float* __restrict__ extra, int M, int Nout) {
    int wave = threadIdx.x >> 6, lane = threadIdx.x & 63;
    int lr = lane & 15, lq = lane >> 4;
    int row0 = (blockIdx.x * 4 + wave) * 16;
    int col0 = blockIdx.y * 64;
    int arow = row0 + lr;
    if (arow >= M) arow = M - 1;
    f32x4 z = {0.f, 0.f, 0.f, 0.f};
    f32x4 acc[4] = {z, z, z, z};
#pragma unroll
    for (int t = 0; t < KD / 32; ++t) {
        short8 a = *(const short8*)(A + (size_t)arow * KD + t * 32 + lq * 8);
#pragma unroll
        for (int cf = 0; cf < 4; ++cf) {
            short8 b = *(const short8*)(BT + (size_t)(col0 + cf * 16 + lr) * KD + t * 32 + lq * 8);
            acc[cf] = __builtin_amdgcn_mfma_f32_16x16x32_bf16(a, b, acc[cf], 0, 0, 0);
        }
    }
#pragma unroll
    for (int cf = 0; cf < 4; ++cf) {
        int col = col0 + cf * 16 + lr;
        float bv = bias[col];
#pragma unroll
        for (int r = 0; r < 4; ++r) {
            int row = row0 + lq * 4 + r;
            if (row >= M) continue;
            float v = acc[cf][r] + bv;
            if (EPI == EPI_F32) {
                ((float*)outp)[(size_t)row * Nout + col] = v;
            } else if (EPI == EPI_RESID) {
                ((float*)outp)[(size_t)row * Nout + col] = v + extra[(size_t)row * D + col];
            } else if (EPI == EPI_SILU_BF) {
                float sg = 1.0f / (1.0f + __expf(-v));
                ((unsigned short*)outp)[(size_t)row * Nout + col] = f2bf(v * sg);
            } else {  // EPI_ADDOUT
                ((float*)outp)[(size_t)row * Nout + col] = v + extra[(size_t)row * D + col];
            }
        }
    }
}

// ---------------- fused edge-proj GEMM + attention score ----------------
// per wave: 16 edges x 128 cols of e = edge_attr @ we (+be), then alpha[e][h] = q[dst].(k[src]+e)/sqrt(8)
__global__ void edge_alpha_kernel(const float* __restrict__ edge_attr, const unsigned short* __restrict__ weT,
                                  const float* __restrict__ be, const int* __restrict__ edge_index,
                                  const float* __restrict__ qkvs, float* __restrict__ alpha) {
    int wave = threadIdx.x >> 6, lane = threadIdx.x & 63;
    int lr = lane & 15, lq = lane >> 4;
    int row0 = (blockIdx.x * 4 + wave) * 16;

    short8 a[4];
#pragma unroll
    for (int t = 0; t < 4; ++t) {
        const float* p = edge_attr + (size_t)(row0 + lr) * D + t * 32 + lq * 8;
        float4 lo = *(const float4*)p;
        float4 hi = *(const float4*)(p + 4);
        short8 av;
        av[0] = f2bf(lo.x); av[1] = f2bf(lo.y); av[2] = f2bf(lo.z); av[3] = f2bf(lo.w);
        av[4] = f2bf(hi.x); av[5] = f2bf(hi.y); av[6] = f2bf(hi.z); av[7] = f2bf(hi.w);
        a[t] = av;
    }
    f32x4 z = {0.f, 0.f, 0.f, 0.f};
    f32x4 acc[8] = {z, z, z, z, z, z, z, z};
#pragma unroll
    for (int cf = 0; cf < 8; ++cf) {
#pragma unroll
        for (int t = 0; t < 4; ++t) {
            short8 b = *(const short8*)(weT + (size_t)(cf * 16 + lr) * D + t * 32 + lq * 8);
            acc[cf] = __builtin_amdgcn_mfma_f32_16x16x32_bf16(a[t], b, acc[cf], 0, 0, 0);
        }
    }
    int srcn[4], dstn[4];
#pragma unroll
    for (int r = 0; r < 4; ++r) {
        int e = row0 + lq * 4 + r;
        srcn[r] = edge_index[e];
        dstn[r] = edge_index[N_EDGES + e];
    }
    const float scale = 0.35355339059327373f;  // 1/sqrt(8)
#pragma unroll
    for (int cf = 0; cf < 8; ++cf) {
        int col = cf * 16 + lr;
        float bev = be[col];
#pragma unroll
        for (int r = 0; r < 4; ++r) {
            float kv = qkvs[(size_t)srcn[r] * 512 + 128 + col];
            float qv = qkvs[(size_t)dstn[r] * 512 + col];
            float p = qv * (kv + acc[cf][r] + bev);
            p += __shfl_xor(p, 1);
            p += __shfl_xor(p, 2);
            p += __shfl_xor(p, 4);
            if ((lane & 7) == 0) {
                int e = row0 + lq * 4 + r;
                alpha[(size_t)e * H + cf * 2 + ((lane >> 3) & 1)] = p * scale;
            }
        }
    }
}

// ---------------- softmax-fused aggregation: one wave per destination node ----------------
__global__ void agg_kernel(const int* __restrict__ row_ptr, const int* __restrict__ eord,
                           const int* __restrict__ edge_index, const float* __restrict__ qkvs,
                           const float* __restrict__ alpha, unsigned short* __restrict__ aggxr) {
    int w = (blockIdx.x * blockDim.x + threadIdx.x) >> 6;
    int lane = threadIdx.x & 63;
    if (w >= N_NODES) return;
    int c = lane * 2;
    int h = lane >> 2;  // head of channels c,c+1
    float acc0 = 0.f, acc1 = 0.f, den = 0.f;
    int s = row_ptr[w], e = row_ptr[w + 1];
    for (int p = s; p < e; ++p) {
        int eid = eord[p];
        int src = edge_index[eid];
        float a = alpha[(size_t)eid * H + h];
        float ex = __expf(a);  // softmax is shift-invariant; |alpha| bounded -> no max pass needed
        float2 vv = *(const float2*)(qkvs + (size_t)src * 512 + 256 + c);
        acc0 += ex * vv.x;
        acc1 += ex * vv.y;
        den += ex;
    }
    float inv = den > 0.f ? 1.0f / den : 0.f;
    float2 xr = *(const float2*)(qkvs + (size_t)w * 512 + 384 + c);
    ushort2 o;
    o.x = f2bf(acc0 * inv + xr.x);
    o.y = f2bf(acc1 * inv + xr.y);
    *(ushort2*)(aggxr + (size_t)w * D + c) = o;
}

extern "C" void kernel_launch(void* const* d_in, const int* in_sizes, int n_in,
                              void* d_out, int out_size, void* d_ws, size_t ws_size,
                              hipStream_t stream) {
    const float* x = (const float*)d_in[0];
    const int* edge_index = (const int*)d_in[1];
    const float* edge_attr = (const float*)d_in[2];
    const float* ln1_g = (const float*)d_in[3];
    const float* ln1_b = (const float*)d_in[4];
    const float* wq = (const float*)d_in[5];  const float* bq = (const float*)d_in[6];
    const float* wk = (const float*)d_in[7];  const float* bk = (const float*)d_in[8];
    const float* wv = (const float*)d_in[9];  const float* bv = (const float*)d_in[10];
    const float* wsw = (const float*)d_in[11]; const float* bs = (const float*)d_in[12];
    const float* we = (const float*)d_in[13]; const float* be = (const float*)d_in[14];
    const float* wp = (const float*)d_in[15]; const float* bp = (const float*)d_in[16];
    const float* mlp_g = (const float*)d_in[17]; const float* mlp_b = (const float*)d_in[18];
    const float* w1 = (const float*)d_in[19]; const float* b1 = (const float*)d_in[20];
    const float* w2 = (const float*)d_in[21]; const float* b2 = (const float*)d_in[22];

    char* base = (char*)d_ws;
    size_t off = 0;
    auto alloc = [&](size_t bytes) -> char* {
        char* p = base + off;
        off = (off + bytes + 255) & ~(size_t)255;
        return p;
    };
    float* qkvs            = (float*)alloc((size_t)N_NODES * 512 * 4);   // q|k|v|xr
    float* alpha           = (float*)alloc((size_t)N_EDGES * H * 4);
    unsigned short* h_bf   = (unsigned short*)alloc((size_t)N_NODES * D * 2);
    unsigned short* aggxr  = (unsigned short*)alloc((size_t)N_NODES * D * 2);
    float* outbuf          = (float*)alloc((size_t)N_NODES * D * 4);
    unsigned short* ln2_bf = (unsigned short*)alloc((size_t)N_NODES * D * 2);
    unsigned short* silu_bf= (unsigned short*)alloc((size_t)N_NODES * DH * 2);
    int* counts            = (int*)alloc((size_t)N_NODES * 4);
    int* row_ptr           = (int*)alloc((size_t)(N_NODES + 1) * 4);
    int* cursor            = (int*)alloc((size_t)N_NODES * 4);
    int* eord              = (int*)alloc((size_t)N_EDGES * 4);
    unsigned short* wqkvsT = (unsigned short*)alloc(512 * 128 * 2);
    unsigned short* weT    = (unsigned short*)alloc(128 * 128 * 2);
    unsigned short* wpT    = (unsigned short*)alloc(128 * 128 * 2);
    unsigned short* w1T    = (unsigned short*)alloc(512 * 128 * 2);
    unsigned short* w2T    = (unsigned short*)alloc(128 * 512 * 2);
    float* bias_qkvs       = (float*)alloc(512 * 4);

    // ---- weight prep ----
    transpose_bf_kernel<<<64, 256, 0, stream>>>(wq, wqkvsT, 128, 128);
    transpose_bf_kernel<<<64, 256, 0, stream>>>(wk, wqkvsT + 128 * 128, 128, 128);
    transpose_bf_kernel<<<64, 256, 0, stream>>>(wv, wqkvsT + 256 * 128, 128, 128);
    transpose_bf_kernel<<<64, 256, 0, stream>>>(wsw, wqkvsT + 384 * 128, 128, 128);
    transpose_bf_kernel<<<64, 256, 0, stream>>>(we, weT, 128, 128);
    transpose_bf_kernel<<<64, 256, 0, stream>>>(wp, wpT, 128, 128);
    transpose_bf_kernel<<<256, 256, 0, stream>>>(w1, w1T, 128, 512);
    transpose_bf_kernel<<<256, 256, 0, stream>>>(w2, w2T, 512, 128);
    bias_concat_kernel<<<2, 256, 0, stream>>>(bq, bk, bv, bs, bias_qkvs);

    // ---- CSR by dst ----
    hipMemsetAsync(counts, 0, (size_t)N_NODES * 4, stream);
    hist_kernel<<<(N_EDGES + 255) / 256, 256, 0, stream>>>(edge_index, counts);
    scan_kernel<<<1, 1024, 0, stream>>>(counts, row_ptr, cursor);
    scatter_kernel<<<(N_EDGES + 255) / 256, 256, 0, stream>>>(edge_index, cursor, eord);

    // ---- node pipeline ----
    ln_kernel<<<(N_NODES + 3) / 4, 256, 0, stream>>>(x, ln1_g, ln1_b, h_bf, N_NODES);

    dim3 g_node((N_NODES + 63) / 64, 8);
    gemm_kernel<128, EPI_F32><<<g_node, 256, 0, stream>>>(h_bf, wqkvsT, bias_qkvs, qkvs, nullptr, N_NODES, 512);

    edge_alpha_kernel<<<N_EDGES / 64, 256, 0, stream>>>(edge_attr, weT, be, edge_index, qkvs, alpha);

    agg_kernel<<<(N_NODES + 3) / 4, 256, 0, stream>>>(row_ptr, eord, edge_index, qkvs, alpha, aggxr);

    dim3 g_out((N_NODES + 63) / 64, 2);
    gemm_kernel<128, EPI_RESID><<<g_out, 256, 0, stream>>>(aggxr, wpT, bp, outbuf, x, N_NODES, 128);

    ln_kernel<<<(N_NODES + 3) / 4, 256, 0, stream>>>(outbuf, mlp_g, mlp_b, ln2_bf, N_NODES);

    dim3 g_mlp1((N_NODES + 63) / 64, 8);
    gemm_kernel<128, EPI_SILU_BF><<<g_mlp1, 256, 0, stream>>>(ln2_bf, w1T, b1, silu_bf, nullptr, N_NODES, 512);

    dim3 g_mlp2((N_NODES + 63) / 64, 2);
    gemm_kernel<512, EPI_ADDOUT><<<g_mlp2, 256, 0, stream>>>(silu_bf, w2T, b2, (float*)d_out, outbuf, N_NODES, 128);
}

// Round 2
// 894.432 us; speedup vs baseline: 1.0895x; 1.0895x over previous
//
#include <hip/hip_runtime.h>

#define N_NODES 50000
#define N_EDGES 800000
#define D 128
#define H 16
#define DH 512

typedef __attribute__((ext_vector_type(8))) short short8;
typedef __attribute__((ext_vector_type(4))) float f32x4;

static __device__ __forceinline__ unsigned short f2bf(float f) {
    unsigned u = __float_as_uint(f);
    u += 0x7FFF + ((u >> 16) & 1);   // round-to-nearest-even
    return (unsigned short)(u >> 16);
}
static __device__ __forceinline__ float bf2f(unsigned short u) {
    return __uint_as_float(((unsigned)u) << 16);
}

// ---------------- LayerNorm (f32 in -> bf16 out), one wave per row ----------------
__global__ void ln_kernel(const float* __restrict__ x, const float* __restrict__ g,
                          const float* __restrict__ b, unsigned short* __restrict__ out, int n) {
    int w = (blockIdx.x * blockDim.x + threadIdx.x) >> 6;
    int lane = threadIdx.x & 63;
    if (w >= n) return;
    float2 v = *(const float2*)(x + (size_t)w * D + lane * 2);
    float s = v.x + v.y, ss = v.x * v.x + v.y * v.y;
#pragma unroll
    for (int off = 32; off; off >>= 1) { s += __shfl_xor(s, off); ss += __shfl_xor(ss, off); }
    float mean = s * (1.0f / D);
    float var = ss * (1.0f / D) - mean * mean;
    float rstd = rsqrtf(var + 1e-5f);
    float2 gv = *(const float2*)(g + lane * 2);
    float2 bv = *(const float2*)(b + lane * 2);
    ushort2 o;
    o.x = f2bf((v.x - mean) * rstd * gv.x + bv.x);
    o.y = f2bf((v.y - mean) * rstd * gv.y + bv.y);
    *(ushort2*)(out + (size_t)w * D + lane * 2) = o;
}

// ---------------- weight transpose+convert: src[in][out] f32 -> dst[out][in] bf16 ----------------
__global__ void transpose_bf_kernel(const float* __restrict__ src, unsigned short* __restrict__ dst,
                                    int in_dim, int out_dim) {
    int idx = blockIdx.x * blockDim.x + threadIdx.x;
    if (idx >= in_dim * out_dim) return;
    int o = idx / in_dim, i = idx - o * in_dim;
    dst[idx] = f2bf(src[i * out_dim + o]);
}

__global__ void bias_concat_kernel(const float* __restrict__ bq, const float* __restrict__ bk,
                                   const float* __restrict__ bv, const float* __restrict__ bs,
                                   float* __restrict__ out) {
    int i = blockIdx.x * blockDim.x + threadIdx.x;
    if (i >= 512) return;
    const float* p = i < 128 ? bq : i < 256 ? bk : i < 384 ? bv : bs;
    out[i] = p[i & 127];
}

// ---------------- CSR build ----------------
__global__ void hist_kernel(const int* __restrict__ edge_index, int* __restrict__ counts) {
    int e = blockIdx.x * blockDim.x + threadIdx.x;
    if (e < N_EDGES) atomicAdd(&counts[edge_index[N_EDGES + e]], 1);
}

// serial-per-thread chunks + one 1024-wide scan (replaces 50x Hillis-Steele passes)
__global__ void scan_kernel(const int* __restrict__ counts, int* __restrict__ row_ptr,
                            int* __restrict__ cursor) {
    __shared__ int sums[1024];
    int tid = threadIdx.x;
    const int CHUNK = (N_NODES + 1023) / 1024;  // 49
    int base = tid * CHUNK;
    int local = 0;
    for (int i = 0; i < CHUNK; ++i) {
        int idx = base + i;
        if (idx < N_NODES) local += counts[idx];
    }
    sums[tid] = local;
    __syncthreads();
    for (int off = 1; off < 1024; off <<= 1) {
        int t = (tid >= off) ? sums[tid - off] : 0;
        __syncthreads();
        sums[tid] += t;
        __syncthreads();
    }
    int run = sums[tid] - local;  // exclusive prefix of this chunk
    for (int i = 0; i < CHUNK; ++i) {
        int idx = base + i;
        if (idx < N_NODES) {
            row_ptr[idx] = run;
            cursor[idx] = run;
            run += counts[idx];
        }
    }
    if (tid == 1023) row_ptr[N_NODES] = run;
}

__global__ void scatter_kernel(const int* __restrict__ edge_index, int* __restrict__ cursor,
                               int* __restrict__ eord) {
    int e = blockIdx.x * blockDim.x + threadIdx.x;
    if (e < N_EDGES) {
        int pos = atomicAdd(&cursor[edge_index[N_EDGES + e]], 1);
        eord[pos] = e;
    }
}

// ---------------- generic bf16 MFMA GEMM: out[M,Nout] = A[M,KD] @ BT[Nout,KD]^T + bias ----------------
enum { EPI_F32 = 0, EPI_RESID = 1, EPI_SILU_BF = 2, EPI_ADDOUT = 3, EPI_BF16 = 4 };

template <int KD, int EPI>
__global__ void gemm_kernel(const unsigned short* __restrict__ A, const unsigned short* __restrict__ BT,
                            const float* __restrict__ bias, void* __restrict__ outp,
                            const float* __restrict__ extra, int M, int Nout) {
    int wave = threadIdx.x >> 6, lane = threadIdx.x & 63;
    int lr = lane & 15, lq = lane >> 4;
    int row0 = (blockIdx.x * 4 + wave) * 16;
    int col0 = blockIdx.y * 64;
    int arow = row0 + lr;
    if (arow >= M) arow = M - 1;
    f32x4 z = {0.f, 0.f, 0.f, 0.f};
    f32x4 acc[4] = {z, z, z, z};
#pragma unroll
    for (int t = 0; t < KD / 32; ++t) {
        short8 a = *(const short8*)(A + (size_t)arow * KD + t * 32 + lq * 8);
#pragma unroll
        for (int cf = 0; cf < 4; ++cf) {
            short8 b = *(const short8*)(BT + (size_t)(col0 + cf * 16 + lr) * KD + t * 32 + lq * 8);
            acc[cf] = __builtin_amdgcn_mfma_f32_16x16x32_bf16(a, b, acc[cf], 0, 0, 0);
        }
    }
#pragma unroll
    for (int cf = 0; cf < 4; ++cf) {
        int col = col0 + cf * 16 + lr;
        float bv = bias[col];
#pragma unroll
        for (int r = 0; r < 4; ++r) {
            int row = row0 + lq * 4 + r;
            if (row >= M) continue;
            float v = acc[cf][r] + bv;
            if (EPI == EPI_F32) {
                ((float*)outp)[(size_t)row * Nout + col] = v;
            } else if (EPI == EPI_RESID) {
                ((float*)outp)[(size_t)row * Nout + col] = v + extra[(size_t)row * D + col];
            } else if (EPI == EPI_SILU_BF) {
                float sg = 1.0f / (1.0f + __expf(-v));
                ((unsigned short*)outp)[(size_t)row * Nout + col] = f2bf(v * sg);
            } else if (EPI == EPI_ADDOUT) {
                ((float*)outp)[(size_t)row * Nout + col] = v + extra[(size_t)row * D + col];
            } else {  // EPI_BF16
                ((unsigned short*)outp)[(size_t)row * Nout + col] = f2bf(v);
            }
        }
    }
}

// ---------------- fused edge-proj GEMM + q.(E+be) score ----------------
// per wave: 16 edges x 128 cols of E = edge_attr @ we; q[dst] staged in LDS via
// coalesced row gathers; alpha_e[e][h] = sum_c q[dst][h][c]*(E[h][c]+be) (unscaled;
// q.k term and 1/sqrt(8) applied in agg_kernel).
__global__ void edge_alpha_kernel(const float* __restrict__ edge_attr, const unsigned short* __restrict__ weT,
                                  const float* __restrict__ be, const int* __restrict__ edge_index,
                                  const unsigned short* __restrict__ qkvs, float* __restrict__ alpha_e) {
    __shared__ unsigned short q_lds[64][128];
    __shared__ float a_lds[64][16];
    int wave = threadIdx.x >> 6, lane = threadIdx.x & 63;
    int lr = lane & 15, lq = lane >> 4;
    int e0 = blockIdx.x * 64;
    int row0 = e0 + wave * 16;

    // phase 0: gather q rows (256B each, coalesced) for this wave's 16 edges
    int half = lane >> 5;   // 0/1: two edges per iteration
    int hl = lane & 31;
    for (int it = 0; it < 8; ++it) {
        int el = wave * 16 + it * 2 + half;
        int dst = edge_index[N_EDGES + e0 + el];
        ushort4 qv = *(const ushort4*)(qkvs + (size_t)dst * 512 + hl * 4);
        *(ushort4*)(&q_lds[el][hl * 4]) = qv;
    }

    // phase 1: E = edge_attr @ weT  (16 edges x 128 cols per wave)
    short8 a[4];
#pragma unroll
    for (int t = 0; t < 4; ++t) {
        const float* p = edge_attr + (size_t)(row0 + lr) * D + t * 32 + lq * 8;
        float4 lo = *(const float4*)p;
        float4 hi = *(const float4*)(p + 4);
        short8 av;
        av[0] = f2bf(lo.x); av[1] = f2bf(lo.y); av[2] = f2bf(lo.z); av[3] = f2bf(lo.w);
        av[4] = f2bf(hi.x); av[5] = f2bf(hi.y); av[6] = f2bf(hi.z); av[7] = f2bf(hi.w);
        a[t] = av;
    }
    f32x4 z = {0.f, 0.f, 0.f, 0.f};
    f32x4 acc[8] = {z, z, z, z, z, z, z, z};
#pragma unroll
    for (int cf = 0; cf < 8; ++cf) {
#pragma unroll
        for (int t = 0; t < 4; ++t) {
            short8 b = *(const short8*)(weT + (size_t)(cf * 16 + lr) * D + t * 32 + lq * 8);
            acc[cf] = __builtin_amdgcn_mfma_f32_16x16x32_bf16(a[t], b, acc[cf], 0, 0, 0);
        }
    }

    __syncthreads();  // q_lds ready (cross-lane)

    // phase 2: per-head dot q.(E+be), reduce over 8 channels, stage into a_lds
#pragma unroll
    for (int cf = 0; cf < 8; ++cf) {
        int col = cf * 16 + lr;
        float bev = be[col];
#pragma unroll
        for (int r = 0; r < 4; ++r) {
            int el = wave * 16 + lq * 4 + r;
            float qv = bf2f(q_lds[el][col]);
            float p = qv * (acc[cf][r] + bev);
            p += __shfl_xor(p, 1);
            p += __shfl_xor(p, 2);
            p += __shfl_xor(p, 4);
            if ((lr & 7) == 0)
                a_lds[el][cf * 2 + (lr >> 3)] = p;
        }
    }

    __syncthreads();  // a_lds ready (cross-lane)

    // phase 3: coalesced alpha store — 1KB contiguous per wave
    int el = wave * 16 + (lane >> 2);
    float4 av = *(const float4*)(&a_lds[el][(lane & 3) * 4]);
    *(float4*)(alpha_e + (size_t)(e0 + el) * 16 + (lane & 3) * 4) = av;
}

// ---------------- softmax-fused aggregation: one wave per destination node ----------------
// alpha[e][h] = (q[dst].k[src] per-head + alpha_e[e][h]) / sqrt(8); softmax over
// incoming edges (shift-invariant, no max pass); agg = sum softmax * v[src]; + xr.
__global__ void agg_kernel(const int* __restrict__ row_ptr, const int* __restrict__ eord,
                           const int* __restrict__ edge_index, const unsigned short* __restrict__ qkvs,
                           const float* __restrict__ alpha_e, unsigned short* __restrict__ aggxr) {
    int w = (blockIdx.x * blockDim.x + threadIdx.x) >> 6;
    int lane = threadIdx.x & 63;
    if (w >= N_NODES) return;
    int c = lane * 2;
    int h = lane >> 2;
    int s = row_ptr[w], e = row_ptr[w + 1];
    int deg = e - s;
    // prefetch up to 64 (eid, src) pairs into registers, broadcast via shfl
    int eid_p = 0, src_p = 0;
    if (lane < deg) { eid_p = eord[s + lane]; src_p = edge_index[eid_p]; }
    ushort2 q2 = *(const ushort2*)(qkvs + (size_t)w * 512 + c);
    float qa = bf2f(q2.x), qb = bf2f(q2.y);
    float acc0 = 0.f, acc1 = 0.f, den = 0.f;
    for (int i = 0; i < deg; ++i) {
        int eid, src;
        if (i < 64) { eid = __shfl(eid_p, i); src = __shfl(src_p, i); }
        else { eid = eord[s + i]; src = edge_index[eid]; }
        ushort2 k2 = *(const ushort2*)(qkvs + (size_t)src * 512 + 128 + c);
        ushort2 v2 = *(const ushort2*)(qkvs + (size_t)src * 512 + 256 + c);
        float pa = qa * bf2f(k2.x) + qb * bf2f(k2.y);
        pa += __shfl_xor(pa, 1);
        pa += __shfl_xor(pa, 2);
        float ae = alpha_e[(size_t)eid * H + h];
        float ex = __expf((pa + ae) * 0.35355339059327373f);
        acc0 += ex * bf2f(v2.x);
        acc1 += ex * bf2f(v2.y);
        den += ex;
    }
    float inv = den > 0.f ? 1.0f / den : 0.f;
    ushort2 x2 = *(const ushort2*)(qkvs + (size_t)w * 512 + 384 + c);
    ushort2 o;
    o.x = f2bf(acc0 * inv + bf2f(x2.x));
    o.y = f2bf(acc1 * inv + bf2f(x2.y));
    *(ushort2*)(aggxr + (size_t)w * D + c) = o;
}

extern "C" void kernel_launch(void* const* d_in, const int* in_sizes, int n_in,
                              void* d_out, int out_size, void* d_ws, size_t ws_size,
                              hipStream_t stream) {
    const float* x = (const float*)d_in[0];
    const int* edge_index = (const int*)d_in[1];
    const float* edge_attr = (const float*)d_in[2];
    const float* ln1_g = (const float*)d_in[3];
    const float* ln1_b = (const float*)d_in[4];
    const float* wq = (const float*)d_in[5];  const float* bq = (const float*)d_in[6];
    const float* wk = (const float*)d_in[7];  const float* bk = (const float*)d_in[8];
    const float* wv = (const float*)d_in[9];  const float* bv = (const float*)d_in[10];
    const float* wsw = (const float*)d_in[11]; const float* bs = (const float*)d_in[12];
    const float* we = (const float*)d_in[13]; const float* be = (const float*)d_in[14];
    const float* wp = (const float*)d_in[15]; const float* bp = (const float*)d_in[16];
    const float* mlp_g = (const float*)d_in[17]; const float* mlp_b = (const float*)d_in[18];
    const float* w1 = (const float*)d_in[19]; const float* b1 = (const float*)d_in[20];
    const float* w2 = (const float*)d_in[21]; const float* b2 = (const float*)d_in[22];

    char* base = (char*)d_ws;
    size_t off = 0;
    auto alloc = [&](size_t bytes) -> char* {
        char* p = base + off;
        off = (off + bytes + 255) & ~(size_t)255;
        return p;
    };
    unsigned short* qkvs   = (unsigned short*)alloc((size_t)N_NODES * 512 * 2);  // q|k|v|xr bf16
    float* alpha_e         = (float*)alloc((size_t)N_EDGES * H * 4);
    unsigned short* h_bf   = (unsigned short*)alloc((size_t)N_NODES * D * 2);
    unsigned short* aggxr  = (unsigned short*)alloc((size_t)N_NODES * D * 2);
    float* outbuf          = (float*)alloc((size_t)N_NODES * D * 4);
    unsigned short* ln2_bf = (unsigned short*)alloc((size_t)N_NODES * D * 2);
    unsigned short* silu_bf= (unsigned short*)alloc((size_t)N_NODES * DH * 2);
    int* counts            = (int*)alloc((size_t)N_NODES * 4);
    int* row_ptr           = (int*)alloc((size_t)(N_NODES + 1) * 4);
    int* cursor            = (int*)alloc((size_t)N_NODES * 4);
    int* eord              = (int*)alloc((size_t)N_EDGES * 4);
    unsigned short* wqkvsT = (unsigned short*)alloc(512 * 128 * 2);
    unsigned short* weT    = (unsigned short*)alloc(128 * 128 * 2);
    unsigned short* wpT    = (unsigned short*)alloc(128 * 128 * 2);
    unsigned short* w1T    = (unsigned short*)alloc(512 * 128 * 2);
    unsigned short* w2T    = (unsigned short*)alloc(128 * 512 * 2);
    float* bias_qkvs       = (float*)alloc(512 * 4);

    // ---- weight prep ----
    transpose_bf_kernel<<<64, 256, 0, stream>>>(wq, wqkvsT, 128, 128);
    transpose_bf_kernel<<<64, 256, 0, stream>>>(wk, wqkvsT + 128 * 128, 128, 128);
    transpose_bf_kernel<<<64, 256, 0, stream>>>(wv, wqkvsT + 256 * 128, 128, 128);
    transpose_bf_kernel<<<64, 256, 0, stream>>>(wsw, wqkvsT + 384 * 128, 128, 128);
    transpose_bf_kernel<<<64, 256, 0, stream>>>(we, weT, 128, 128);
    transpose_bf_kernel<<<64, 256, 0, stream>>>(wp, wpT, 128, 128);
    transpose_bf_kernel<<<256, 256, 0, stream>>>(w1, w1T, 128, 512);
    transpose_bf_kernel<<<256, 256, 0, stream>>>(w2, w2T, 512, 128);
    bias_concat_kernel<<<2, 256, 0, stream>>>(bq, bk, bv, bs, bias_qkvs);

    // ---- CSR by dst ----
    hipMemsetAsync(counts, 0, (size_t)N_NODES * 4, stream);
    hist_kernel<<<(N_EDGES + 255) / 256, 256, 0, stream>>>(edge_index, counts);
    scan_kernel<<<1, 1024, 0, stream>>>(counts, row_ptr, cursor);
    scatter_kernel<<<(N_EDGES + 255) / 256, 256, 0, stream>>>(edge_index, cursor, eord);

    // ---- node pipeline ----
    ln_kernel<<<(N_NODES + 3) / 4, 256, 0, stream>>>(x, ln1_g, ln1_b, h_bf, N_NODES);

    dim3 g_node((N_NODES + 63) / 64, 8);
    gemm_kernel<128, EPI_BF16><<<g_node, 256, 0, stream>>>(h_bf, wqkvsT, bias_qkvs, qkvs, nullptr, N_NODES, 512);

    edge_alpha_kernel<<<N_EDGES / 64, 256, 0, stream>>>(edge_attr, weT, be, edge_index, qkvs, alpha_e);

    agg_kernel<<<(N_NODES + 3) / 4, 256, 0, stream>>>(row_ptr, eord, edge_index, qkvs, alpha_e, aggxr);

    dim3 g_out((N_NODES + 63) / 64, 2);
    gemm_kernel<128, EPI_RESID><<<g_out, 256, 0, stream>>>(aggxr, wpT, bp, outbuf, x, N_NODES, 128);

    ln_kernel<<<(N_NODES + 3) / 4, 256, 0, stream>>>(outbuf, mlp_g, mlp_b, ln2_bf, N_NODES);

    dim3 g_mlp1((N_NODES + 63) / 64, 8);
    gemm_kernel<128, EPI_SILU_BF><<<g_mlp1, 256, 0, stream>>>(ln2_bf, w1T, b1, silu_bf, nullptr, N_NODES, 512);

    dim3 g_mlp2((N_NODES + 63) / 64, 2);
    gemm_kernel<512, EPI_ADDOUT><<<g_mlp2, 256, 0, stream>>>(silu_bf, w2T, b2, (float*)d_out, outbuf, N_NODES, 128);
}

// Round 3
// 884.824 us; speedup vs baseline: 1.1013x; 1.0109x over previous
//
#include <hip/hip_runtime.h>

#define N_NODES 50000
#define N_EDGES 800000
#define D 128
#define H 16
#define DH 512

typedef __attribute__((ext_vector_type(8))) short short8;
typedef __attribute__((ext_vector_type(4))) float f32x4;

static __device__ __forceinline__ unsigned short f2bf(float f) {
    unsigned u = __float_as_uint(f);
    u += 0x7FFF + ((u >> 16) & 1);   // round-to-nearest-even
    return (unsigned short)(u >> 16);
}
static __device__ __forceinline__ float bf2f(unsigned short u) {
    return __uint_as_float(((unsigned)u) << 16);
}

// ---------------- LayerNorm (f32 in -> bf16 out), one wave per row ----------------
__global__ void ln_kernel(const float* __restrict__ x, const float* __restrict__ g,
                          const float* __restrict__ b, unsigned short* __restrict__ out, int n) {
    int w = (blockIdx.x * blockDim.x + threadIdx.x) >> 6;
    int lane = threadIdx.x & 63;
    if (w >= n) return;
    float2 v = *(const float2*)(x + (size_t)w * D + lane * 2);
    float s = v.x + v.y, ss = v.x * v.x + v.y * v.y;
#pragma unroll
    for (int off = 32; off; off >>= 1) { s += __shfl_xor(s, off); ss += __shfl_xor(ss, off); }
    float mean = s * (1.0f / D);
    float var = ss * (1.0f / D) - mean * mean;
    float rstd = rsqrtf(var + 1e-5f);
    float2 gv = *(const float2*)(g + lane * 2);
    float2 bv = *(const float2*)(b + lane * 2);
    ushort2 o;
    o.x = f2bf((v.x - mean) * rstd * gv.x + bv.x);
    o.y = f2bf((v.y - mean) * rstd * gv.y + bv.y);
    *(ushort2*)(out + (size_t)w * D + lane * 2) = o;
}

// ---------------- fused weight prep: all transposes + bias concat in ONE launch ----------------
__global__ void prep_kernel(const float* __restrict__ wq, const float* __restrict__ wk,
                            const float* __restrict__ wv, const float* __restrict__ ws,
                            const float* __restrict__ we, const float* __restrict__ wp,
                            const float* __restrict__ w1, const float* __restrict__ w2,
                            const float* __restrict__ bq, const float* __restrict__ bk,
                            const float* __restrict__ bv, const float* __restrict__ bs,
                            unsigned short* __restrict__ wqkvsT, unsigned short* __restrict__ weT,
                            unsigned short* __restrict__ wpT, unsigned short* __restrict__ w1T,
                            unsigned short* __restrict__ w2T, float* __restrict__ bias_qkvs) {
    int idx = blockIdx.x * blockDim.x + threadIdx.x;
    if (idx < 65536) {                       // wq|wk|wv|ws -> wqkvsT [512][128]
        int seg = idx >> 14, r = idx & 16383;
        const float* src = seg == 0 ? wq : seg == 1 ? wk : seg == 2 ? wv : ws;
        int o = r >> 7, i = r & 127;
        wqkvsT[idx] = f2bf(src[i * 128 + o]);
    } else if (idx < 81920) {                // weT [128][128]
        int r = idx - 65536; int o = r >> 7, i = r & 127;
        weT[r] = f2bf(we[i * 128 + o]);
    } else if (idx < 98304) {                // wpT [128][128]
        int r = idx - 81920; int o = r >> 7, i = r & 127;
        wpT[r] = f2bf(wp[i * 128 + o]);
    } else if (idx < 163840) {               // w1T [512][128], src w1 [128][512]
        int r = idx - 98304; int o = r >> 7, i = r & 127;
        w1T[r] = f2bf(w1[i * 512 + o]);
    } else if (idx < 229376) {               // w2T [128][512], src w2 [512][128]
        int r = idx - 163840; int o = r >> 9, i = r & 511;
        w2T[r] = f2bf(w2[i * 128 + o]);
    } else if (idx < 229888) {               // bias concat
        int r = idx - 229376;
        const float* p = r < 128 ? bq : r < 256 ? bk : r < 384 ? bv : bs;
        bias_qkvs[r] = p[r & 127];
    }
}

// ---------------- CSR build ----------------
__global__ void hist_kernel(const int* __restrict__ edge_index, int* __restrict__ counts) {
    int e = blockIdx.x * blockDim.x + threadIdx.x;
    if (e < N_EDGES) atomicAdd(&counts[edge_index[N_EDGES + e]], 1);
}

__global__ void scan_kernel(const int* __restrict__ counts, int* __restrict__ row_ptr,
                            int* __restrict__ cursor) {
    __shared__ int sums[1024];
    int tid = threadIdx.x;
    const int CHUNK = (N_NODES + 1023) / 1024;  // 49
    int base = tid * CHUNK;
    int local = 0;
    for (int i = 0; i < CHUNK; ++i) {
        int idx = base + i;
        if (idx < N_NODES) local += counts[idx];
    }
    sums[tid] = local;
    __syncthreads();
    for (int off = 1; off < 1024; off <<= 1) {
        int t = (tid >= off) ? sums[tid - off] : 0;
        __syncthreads();
        sums[tid] += t;
        __syncthreads();
    }
    int run = sums[tid] - local;
    for (int i = 0; i < CHUNK; ++i) {
        int idx = base + i;
        if (idx < N_NODES) {
            row_ptr[idx] = run;
            cursor[idx] = run;
            run += counts[idx];
        }
    }
    if (tid == 1023) row_ptr[N_NODES] = run;
}

// also emits src_ord/dst_ord so downstream kernels never chase edge_index again
__global__ void scatter_kernel(const int* __restrict__ edge_index, int* __restrict__ cursor,
                               int* __restrict__ eord, int* __restrict__ src_ord,
                               int* __restrict__ dst_ord) {
    int e = blockIdx.x * blockDim.x + threadIdx.x;
    if (e < N_EDGES) {
        int dst = edge_index[N_EDGES + e];
        int pos = atomicAdd(&cursor[dst], 1);
        eord[pos] = e;
        src_ord[pos] = edge_index[e];
        dst_ord[pos] = dst;
    }
}

// ---------------- generic bf16 MFMA GEMM ----------------
enum { EPI_F32 = 0, EPI_RESID = 1, EPI_SILU_BF = 2, EPI_ADDOUT = 3, EPI_BF16 = 4 };

template <int KD, int EPI>
__global__ void gemm_kernel(const unsigned short* __restrict__ A, const unsigned short* __restrict__ BT,
                            const float* __restrict__ bias, void* __restrict__ outp,
                            const float* __restrict__ extra, int M, int Nout) {
    int wave = threadIdx.x >> 6, lane = threadIdx.x & 63;
    int lr = lane & 15, lq = lane >> 4;
    int row0 = (blockIdx.x * 4 + wave) * 16;
    int col0 = blockIdx.y * 64;
    int arow = row0 + lr;
    if (arow >= M) arow = M - 1;
    f32x4 z = {0.f, 0.f, 0.f, 0.f};
    f32x4 acc[4] = {z, z, z, z};
#pragma unroll
    for (int t = 0; t < KD / 32; ++t) {
        short8 a = *(const short8*)(A + (size_t)arow * KD + t * 32 + lq * 8);
#pragma unroll
        for (int cf = 0; cf < 4; ++cf) {
            short8 b = *(const short8*)(BT + (size_t)(col0 + cf * 16 + lr) * KD + t * 32 + lq * 8);
            acc[cf] = __builtin_amdgcn_mfma_f32_16x16x32_bf16(a, b, acc[cf], 0, 0, 0);
        }
    }
#pragma unroll
    for (int cf = 0; cf < 4; ++cf) {
        int col = col0 + cf * 16 + lr;
        float bv = bias[col];
#pragma unroll
        for (int r = 0; r < 4; ++r) {
            int row = row0 + lq * 4 + r;
            if (row >= M) continue;
            float v = acc[cf][r] + bv;
            if (EPI == EPI_F32) {
                ((float*)outp)[(size_t)row * Nout + col] = v;
            } else if (EPI == EPI_RESID) {
                ((float*)outp)[(size_t)row * Nout + col] = v + extra[(size_t)row * D + col];
            } else if (EPI == EPI_SILU_BF) {
                float sg = 1.0f / (1.0f + __expf(-v));
                ((unsigned short*)outp)[(size_t)row * Nout + col] = f2bf(v * sg);
            } else if (EPI == EPI_ADDOUT) {
                ((float*)outp)[(size_t)row * Nout + col] = v + extra[(size_t)row * D + col];
            } else {  // EPI_BF16
                ((unsigned short*)outp)[(size_t)row * Nout + col] = f2bf(v);
            }
        }
    }
}

// ---------------- fused edge GEMM + FULL score + exp, in CSR slot order ----------------
// per wave: 16 slots. E = edge_attr[eord[slot]] @ weT; q[dst] (sorted -> L1 hits) and
// k[src] rows staged in LDS; ex[slot][h] = exp(q.(k+E+be)/sqrt(8)) written coalesced.
// All LDS rows are wave-private; __syncthreads only for write->read visibility safety.
__global__ void edge_score_kernel(const float* __restrict__ edge_attr,
                                  const unsigned short* __restrict__ weT,
                                  const float* __restrict__ be, const int* __restrict__ eord,
                                  const int* __restrict__ src_ord, const int* __restrict__ dst_ord,
                                  const unsigned short* __restrict__ qkvs, float* __restrict__ ex) {
    __shared__ unsigned short q_lds[64][132];  // +4 pad: 4*rowstride = 8 mod 32 banks -> conflict-free reads
    __shared__ unsigned short k_lds[64][132];
    __shared__ float ex_lds[64][16];
    int wave = threadIdx.x >> 6, lane = threadIdx.x & 63;
    int lr = lane & 15, lq = lane >> 4;
    int s0 = blockIdx.x * 64;

    int eid = eord[s0 + wave * 16 + lr];

    // stage q[dst], k[src] rows (256B coalesced each; dst sorted -> cache-friendly)
    int half = lane >> 5, hl = lane & 31;
#pragma unroll
    for (int it = 0; it < 8; ++it) {
        int el = wave * 16 + it * 2 + half;
        int dst = dst_ord[s0 + el];
        int src = src_ord[s0 + el];
        *(ushort4*)(&q_lds[el][hl * 4]) = *(const ushort4*)(qkvs + (size_t)dst * 512 + hl * 4);
        *(ushort4*)(&k_lds[el][hl * 4]) = *(const ushort4*)(qkvs + (size_t)src * 512 + 128 + hl * 4);
    }

    // A fragments from gathered edge_attr rows (512B/row, fully consumed)
    short8 a[4];
#pragma unroll
    for (int t = 0; t < 4; ++t) {
        const float* p = edge_attr + (size_t)eid * D + t * 32 + lq * 8;
        float4 lo = *(const float4*)p;
        float4 hi = *(const float4*)(p + 4);
        short8 av;
        av[0] = f2bf(lo.x); av[1] = f2bf(lo.y); av[2] = f2bf(lo.z); av[3] = f2bf(lo.w);
        av[4] = f2bf(hi.x); av[5] = f2bf(hi.y); av[6] = f2bf(hi.z); av[7] = f2bf(hi.w);
        a[t] = av;
    }
    f32x4 z = {0.f, 0.f, 0.f, 0.f};
    f32x4 acc[8] = {z, z, z, z, z, z, z, z};
#pragma unroll
    for (int cf = 0; cf < 8; ++cf) {
#pragma unroll
        for (int t = 0; t < 4; ++t) {
            short8 b = *(const short8*)(weT + (size_t)(cf * 16 + lr) * D + t * 32 + lq * 8);
            acc[cf] = __builtin_amdgcn_mfma_f32_16x16x32_bf16(a[t], b, acc[cf], 0, 0, 0);
        }
    }

    __syncthreads();

    const float scale = 0.35355339059327373f;  // 1/sqrt(8)
#pragma unroll
    for (int cf = 0; cf < 8; ++cf) {
        int col = cf * 16 + lr;
        float bev = be[col];
#pragma unroll
        for (int r = 0; r < 4; ++r) {
            int el = wave * 16 + lq * 4 + r;
            float qv = bf2f(q_lds[el][col]);
            float kv = bf2f(k_lds[el][col]);
            float p = qv * (kv + acc[cf][r] + bev);
            p += __shfl_xor(p, 1);
            p += __shfl_xor(p, 2);
            p += __shfl_xor(p, 4);
            if ((lr & 7) == 0)
                ex_lds[el][cf * 2 + (lr >> 3)] = __expf(p * scale);  // shift-invariant softmax, no max pass
        }
    }

    __syncthreads();

    // coalesced ex store: 1KB contiguous per wave, slot-sequential
    int el = wave * 16 + (lane >> 2);
    float4 av = *(const float4*)(&ex_lds[el][(lane & 3) * 4]);
    *(float4*)(ex + (size_t)(s0 + el) * 16 + (lane & 3) * 4) = av;
}

// ---------------- aggregation: one wave per node; sequential ex, v-row gather only ----------------
__global__ void agg_kernel(const int* __restrict__ row_ptr, const int* __restrict__ src_ord,
                           const float* __restrict__ ex, const unsigned short* __restrict__ qkvs,
                           unsigned short* __restrict__ aggxr) {
    int w = (blockIdx.x * blockDim.x + threadIdx.x) >> 6;
    int lane = threadIdx.x & 63;
    if (w >= N_NODES) return;
    int c = lane * 2, h = lane >> 2;
    int s = row_ptr[w], e = row_ptr[w + 1], deg = e - s;
    int src_p = (lane < deg) ? src_ord[s + lane] : 0;
    float acc0 = 0.f, acc1 = 0.f, den = 0.f;
    for (int i = 0; i < deg; ++i) {
        int src = (i < 64) ? __shfl(src_p, i) : src_ord[s + i];
        float exv = ex[(size_t)(s + i) * H + h];
        ushort2 v2 = *(const ushort2*)(qkvs + (size_t)src * 512 + 256 + c);
        acc0 += exv * bf2f(v2.x);
        acc1 += exv * bf2f(v2.y);
        den += exv;
    }
    float inv = den > 0.f ? 1.0f / den : 0.f;
    ushort2 x2 = *(const ushort2*)(qkvs + (size_t)w * 512 + 384 + c);
    ushort2 o;
    o.x = f2bf(acc0 * inv + bf2f(x2.x));
    o.y = f2bf(acc1 * inv + bf2f(x2.y));
    *(ushort2*)(aggxr + (size_t)w * D + c) = o;
}

extern "C" void kernel_launch(void* const* d_in, const int* in_sizes, int n_in,
                              void* d_out, int out_size, void* d_ws, size_t ws_size,
                              hipStream_t stream) {
    const float* x = (const float*)d_in[0];
    const int* edge_index = (const int*)d_in[1];
    const float* edge_attr = (const float*)d_in[2];
    const float* ln1_g = (const float*)d_in[3];
    const float* ln1_b = (const float*)d_in[4];
    const float* wq = (const float*)d_in[5];  const float* bq = (const float*)d_in[6];
    const float* wk = (const float*)d_in[7];  const float* bk = (const float*)d_in[8];
    const float* wv = (const float*)d_in[9];  const float* bv = (const float*)d_in[10];
    const float* wsw = (const float*)d_in[11]; const float* bs = (const float*)d_in[12];
    const float* we = (const float*)d_in[13]; const float* be = (const float*)d_in[14];
    const float* wp = (const float*)d_in[15]; const float* bp = (const float*)d_in[16];
    const float* mlp_g = (const float*)d_in[17]; const float* mlp_b = (const float*)d_in[18];
    const float* w1 = (const float*)d_in[19]; const float* b1 = (const float*)d_in[20];
    const float* w2 = (const float*)d_in[21]; const float* b2 = (const float*)d_in[22];

    char* base = (char*)d_ws;
    size_t off = 0;
    auto alloc = [&](size_t bytes) -> char* {
        char* p = base + off;
        off = (off + bytes + 255) & ~(size_t)255;
        return p;
    };
    unsigned short* qkvs   = (unsigned short*)alloc((size_t)N_NODES * 512 * 2);  // q|k|v|xr bf16
    float* ex_buf          = (float*)alloc((size_t)N_EDGES * H * 4);
    unsigned short* h_bf   = (unsigned short*)alloc((size_t)N_NODES * D * 2);
    unsigned short* aggxr  = (unsigned short*)alloc((size_t)N_NODES * D * 2);
    float* outbuf          = (float*)alloc((size_t)N_NODES * D * 4);
    unsigned short* ln2_bf = (unsigned short*)alloc((size_t)N_NODES * D * 2);
    unsigned short* silu_bf= (unsigned short*)alloc((size_t)N_NODES * DH * 2);
    int* counts            = (int*)alloc((size_t)N_NODES * 4);
    int* row_ptr           = (int*)alloc((size_t)(N_NODES + 1) * 4);
    int* cursor            = (int*)alloc((size_t)N_NODES * 4);
    int* eord              = (int*)alloc((size_t)N_EDGES * 4);
    int* src_ord           = (int*)alloc((size_t)N_EDGES * 4);
    int* dst_ord           = (int*)alloc((size_t)N_EDGES * 4);
    unsigned short* wqkvsT = (unsigned short*)alloc(512 * 128 * 2);
    unsigned short* weT    = (unsigned short*)alloc(128 * 128 * 2);
    unsigned short* wpT    = (unsigned short*)alloc(128 * 128 * 2);
    unsigned short* w1T    = (unsigned short*)alloc(512 * 128 * 2);
    unsigned short* w2T    = (unsigned short*)alloc(128 * 512 * 2);
    float* bias_qkvs       = (float*)alloc(512 * 4);

    // ---- weight prep (single launch) ----
    prep_kernel<<<898, 256, 0, stream>>>(wq, wk, wv, wsw, we, wp, w1, w2, bq, bk, bv, bs,
                                         wqkvsT, weT, wpT, w1T, w2T, bias_qkvs);

    // ---- CSR by dst ----
    hipMemsetAsync(counts, 0, (size_t)N_NODES * 4, stream);
    hist_kernel<<<(N_EDGES + 255) / 256, 256, 0, stream>>>(edge_index, counts);
    scan_kernel<<<1, 1024, 0, stream>>>(counts, row_ptr, cursor);
    scatter_kernel<<<(N_EDGES + 255) / 256, 256, 0, stream>>>(edge_index, cursor, eord, src_ord, dst_ord);

    // ---- node pipeline ----
    ln_kernel<<<(N_NODES + 3) / 4, 256, 0, stream>>>(x, ln1_g, ln1_b, h_bf, N_NODES);

    dim3 g_node((N_NODES + 63) / 64, 8);
    gemm_kernel<128, EPI_BF16><<<g_node, 256, 0, stream>>>(h_bf, wqkvsT, bias_qkvs, qkvs, nullptr, N_NODES, 512);

    edge_score_kernel<<<N_EDGES / 64, 256, 0, stream>>>(edge_attr, weT, be, eord, src_ord, dst_ord, qkvs, ex_buf);

    agg_kernel<<<(N_NODES + 3) / 4, 256, 0, stream>>>(row_ptr, src_ord, ex_buf, qkvs, aggxr);

    dim3 g_out((N_NODES + 63) / 64, 2);
    gemm_kernel<128, EPI_RESID><<<g_out, 256, 0, stream>>>(aggxr, wpT, bp, outbuf, x, N_NODES, 128);

    ln_kernel<<<(N_NODES + 3) / 4, 256, 0, stream>>>(outbuf, mlp_g, mlp_b, ln2_bf, N_NODES);

    dim3 g_mlp1((N_NODES + 63) / 64, 8);
    gemm_kernel<128, EPI_SILU_BF><<<g_mlp1, 256, 0, stream>>>(ln2_bf, w1T, b1, silu_bf, nullptr, N_NODES, 512);

    dim3 g_mlp2((N_NODES + 63) / 64, 2);
    gemm_kernel<512, EPI_ADDOUT><<<g_mlp2, 256, 0, stream>>>(silu_bf, w2T, b2, (float*)d_out, outbuf, N_NODES, 128);
}

// Round 4
// 884.248 us; speedup vs baseline: 1.1020x; 1.0007x over previous
//
#include <hip/hip_runtime.h>

#define N_NODES 50000
#define N_EDGES 800000
#define D 128
#define H 16
#define DH 512

typedef __attribute__((ext_vector_type(8))) short short8;
typedef __attribute__((ext_vector_type(4))) float f32x4;

static __device__ __forceinline__ unsigned short f2bf(float f) {
    unsigned u = __float_as_uint(f);
    u += 0x7FFF + ((u >> 16) & 1);   // round-to-nearest-even
    return (unsigned short)(u >> 16);
}
static __device__ __forceinline__ float bf2f(unsigned short u) {
    return __uint_as_float(((unsigned)u) << 16);
}

// ---------------- LayerNorm (f32 in -> bf16 out), one wave per row ----------------
__global__ void ln_kernel(const float* __restrict__ x, const float* __restrict__ g,
                          const float* __restrict__ b, unsigned short* __restrict__ out, int n) {
    int w = (blockIdx.x * blockDim.x + threadIdx.x) >> 6;
    int lane = threadIdx.x & 63;
    if (w >= n) return;
    float2 v = *(const float2*)(x + (size_t)w * D + lane * 2);
    float s = v.x + v.y, ss = v.x * v.x + v.y * v.y;
#pragma unroll
    for (int off = 32; off; off >>= 1) { s += __shfl_xor(s, off); ss += __shfl_xor(ss, off); }
    float mean = s * (1.0f / D);
    float var = ss * (1.0f / D) - mean * mean;
    float rstd = rsqrtf(var + 1e-5f);
    float2 gv = *(const float2*)(g + lane * 2);
    float2 bv = *(const float2*)(b + lane * 2);
    ushort2 o;
    o.x = f2bf((v.x - mean) * rstd * gv.x + bv.x);
    o.y = f2bf((v.y - mean) * rstd * gv.y + bv.y);
    *(ushort2*)(out + (size_t)w * D + lane * 2) = o;
}

// ---------------- fused weight prep: all transposes + bias concat in ONE launch ----------------
__global__ void prep_kernel(const float* __restrict__ wq, const float* __restrict__ wk,
                            const float* __restrict__ wv, const float* __restrict__ ws,
                            const float* __restrict__ we, const float* __restrict__ wp,
                            const float* __restrict__ w1, const float* __restrict__ w2,
                            const float* __restrict__ bq, const float* __restrict__ bk,
                            const float* __restrict__ bv, const float* __restrict__ bs,
                            unsigned short* __restrict__ wqkvsT, unsigned short* __restrict__ weT,
                            unsigned short* __restrict__ wpT, unsigned short* __restrict__ w1T,
                            unsigned short* __restrict__ w2T, float* __restrict__ bias_qkvs) {
    int idx = blockIdx.x * blockDim.x + threadIdx.x;
    if (idx < 65536) {                       // wq|wk|wv|ws -> wqkvsT [512][128]
        int seg = idx >> 14, r = idx & 16383;
        const float* src = seg == 0 ? wq : seg == 1 ? wk : seg == 2 ? wv : ws;
        int o = r >> 7, i = r & 127;
        wqkvsT[idx] = f2bf(src[i * 128 + o]);
    } else if (idx < 81920) {                // weT [128][128]
        int r = idx - 65536; int o = r >> 7, i = r & 127;
        weT[r] = f2bf(we[i * 128 + o]);
    } else if (idx < 98304) {                // wpT [128][128]
        int r = idx - 81920; int o = r >> 7, i = r & 127;
        wpT[r] = f2bf(wp[i * 128 + o]);
    } else if (idx < 163840) {               // w1T [512][128], src w1 [128][512]
        int r = idx - 98304; int o = r >> 7, i = r & 127;
        w1T[r] = f2bf(w1[i * 512 + o]);
    } else if (idx < 229376) {               // w2T [128][512], src w2 [512][128]
        int r = idx - 163840; int o = r >> 9, i = r & 511;
        w2T[r] = f2bf(w2[i * 128 + o]);
    } else if (idx < 229888) {               // bias concat
        int r = idx - 229376;
        const float* p = r < 128 ? bq : r < 256 ? bk : r < 384 ? bv : bs;
        bias_qkvs[r] = p[r & 127];
    }
}

// ---------------- CSR build ----------------
__global__ void hist_kernel(const int* __restrict__ edge_index, int* __restrict__ counts) {
    int e = blockIdx.x * blockDim.x + threadIdx.x;
    if (e < N_EDGES) atomicAdd(&counts[edge_index[N_EDGES + e]], 1);
}

__global__ void scan_kernel(const int* __restrict__ counts, int* __restrict__ row_ptr,
                            int* __restrict__ cursor) {
    __shared__ int sums[1024];
    int tid = threadIdx.x;
    const int CHUNK = (N_NODES + 1023) / 1024;  // 49
    int base = tid * CHUNK;
    int local = 0;
    for (int i = 0; i < CHUNK; ++i) {
        int idx = base + i;
        if (idx < N_NODES) local += counts[idx];
    }
    sums[tid] = local;
    __syncthreads();
    for (int off = 1; off < 1024; off <<= 1) {
        int t = (tid >= off) ? sums[tid - off] : 0;
        __syncthreads();
        sums[tid] += t;
        __syncthreads();
    }
    int run = sums[tid] - local;
    for (int i = 0; i < CHUNK; ++i) {
        int idx = base + i;
        if (idx < N_NODES) {
            row_ptr[idx] = run;
            cursor[idx] = run;
            run += counts[idx];
        }
    }
    if (tid == 1023) row_ptr[N_NODES] = run;
}

// also emits src_ord/dst_ord so downstream kernels never chase edge_index again
__global__ void scatter_kernel(const int* __restrict__ edge_index, int* __restrict__ cursor,
                               int* __restrict__ eord, int* __restrict__ src_ord,
                               int* __restrict__ dst_ord) {
    int e = blockIdx.x * blockDim.x + threadIdx.x;
    if (e < N_EDGES) {
        int dst = edge_index[N_EDGES + e];
        int pos = atomicAdd(&cursor[dst], 1);
        eord[pos] = e;
        src_ord[pos] = edge_index[e];
        dst_ord[pos] = dst;
    }
}

// ---------------- generic bf16 MFMA GEMM ----------------
enum { EPI_F32 = 0, EPI_RESID = 1, EPI_SILU_BF = 2, EPI_ADDOUT = 3, EPI_BF16 = 4 };

template <int KD, int EPI>
__global__ void gemm_kernel(const unsigned short* __restrict__ A, const unsigned short* __restrict__ BT,
                            const float* __restrict__ bias, void* __restrict__ outp,
                            const float* __restrict__ extra, int M, int Nout) {
    int wave = threadIdx.x >> 6, lane = threadIdx.x & 63;
    int lr = lane & 15, lq = lane >> 4;
    int row0 = (blockIdx.x * 4 + wave) * 16;
    int col0 = blockIdx.y * 64;
    int arow = row0 + lr;
    if (arow >= M) arow = M - 1;
    f32x4 z = {0.f, 0.f, 0.f, 0.f};
    f32x4 acc[4] = {z, z, z, z};
#pragma unroll
    for (int t = 0; t < KD / 32; ++t) {
        short8 a = *(const short8*)(A + (size_t)arow * KD + t * 32 + lq * 8);
#pragma unroll
        for (int cf = 0; cf < 4; ++cf) {
            short8 b = *(const short8*)(BT + (size_t)(col0 + cf * 16 + lr) * KD + t * 32 + lq * 8);
            acc[cf] = __builtin_amdgcn_mfma_f32_16x16x32_bf16(a, b, acc[cf], 0, 0, 0);
        }
    }
#pragma unroll
    for (int cf = 0; cf < 4; ++cf) {
        int col = col0 + cf * 16 + lr;
        float bv = bias[col];
#pragma unroll
        for (int r = 0; r < 4; ++r) {
            int row = row0 + lq * 4 + r;
            if (row >= M) continue;
            float v = acc[cf][r] + bv;
            if (EPI == EPI_F32) {
                ((float*)outp)[(size_t)row * Nout + col] = v;
            } else if (EPI == EPI_RESID) {
                ((float*)outp)[(size_t)row * Nout + col] = v + extra[(size_t)row * D + col];
            } else if (EPI == EPI_SILU_BF) {
                float sg = 1.0f / (1.0f + __expf(-v));
                ((unsigned short*)outp)[(size_t)row * Nout + col] = f2bf(v * sg);
            } else if (EPI == EPI_ADDOUT) {
                ((float*)outp)[(size_t)row * Nout + col] = v + extra[(size_t)row * D + col];
            } else {  // EPI_BF16
                ((unsigned short*)outp)[(size_t)row * Nout + col] = f2bf(v);
            }
        }
    }
}

// ---------------- fused edge GEMM + FULL score + exp, in CSR slot order ----------------
// per wave: 16 slots. E = edge_attr[eord[slot]] @ weT; q[dst] (sorted -> L1 hits) and
// k[src] rows staged in LDS; ex[slot][h] = exp(q.(k+E+be)/sqrt(8)) written coalesced.
// All LDS rows are wave-private; __syncthreads only for write->read visibility safety.
__global__ void edge_score_kernel(const float* __restrict__ edge_attr,
                                  const unsigned short* __restrict__ weT,
                                  const float* __restrict__ be, const int* __restrict__ eord,
                                  const int* __restrict__ src_ord, const int* __restrict__ dst_ord,
                                  const unsigned short* __restrict__ qkvs, float* __restrict__ ex) {
    __shared__ unsigned short q_lds[64][132];  // +4 pad: 4*rowstride = 8 mod 32 banks -> conflict-free reads
    __shared__ unsigned short k_lds[64][132];
    __shared__ float ex_lds[64][16];
    int wave = threadIdx.x >> 6, lane = threadIdx.x & 63;
    int lr = lane & 15, lq = lane >> 4;
    int s0 = blockIdx.x * 64;

    int eid = eord[s0 + wave * 16 + lr];

    // stage q[dst], k[src] rows (256B coalesced each; dst sorted -> cache-friendly)
    int half = lane >> 5, hl = lane & 31;
#pragma unroll
    for (int it = 0; it < 8; ++it) {
        int el = wave * 16 + it * 2 + half;
        int dst = dst_ord[s0 + el];
        int src = src_ord[s0 + el];
        *(ushort4*)(&q_lds[el][hl * 4]) = *(const ushort4*)(qkvs + (size_t)dst * 512 + hl * 4);
        *(ushort4*)(&k_lds[el][hl * 4]) = *(const ushort4*)(qkvs + (size_t)src * 512 + 128 + hl * 4);
    }

    // A fragments from gathered edge_attr rows (512B/row, fully consumed)
    short8 a[4];
#pragma unroll
    for (int t = 0; t < 4; ++t) {
        const float* p = edge_attr + (size_t)eid * D + t * 32 + lq * 8;
        float4 lo = *(const float4*)p;
        float4 hi = *(const float4*)(p + 4);
        short8 av;
        av[0] = f2bf(lo.x); av[1] = f2bf(lo.y); av[2] = f2bf(lo.z); av[3] = f2bf(lo.w);
        av[4] = f2bf(hi.x); av[5] = f2bf(hi.y); av[6] = f2bf(hi.z); av[7] = f2bf(hi.w);
        a[t] = av;
    }
    f32x4 z = {0.f, 0.f, 0.f, 0.f};
    f32x4 acc[8] = {z, z, z, z, z, z, z, z};
#pragma unroll
    for (int cf = 0; cf < 8; ++cf) {
#pragma unroll
        for (int t = 0; t < 4; ++t) {
            short8 b = *(const short8*)(weT + (size_t)(cf * 16 + lr) * D + t * 32 + lq * 8);
            acc[cf] = __builtin_amdgcn_mfma_f32_16x16x32_bf16(a[t], b, acc[cf], 0, 0, 0);
        }
    }

    __syncthreads();

    const float scale = 0.35355339059327373f;  // 1/sqrt(8)
#pragma unroll
    for (int cf = 0; cf < 8; ++cf) {
        int col = cf * 16 + lr;
        float bev = be[col];
#pragma unroll
        for (int r = 0; r < 4; ++r) {
            int el = wave * 16 + lq * 4 + r;
            float qv = bf2f(q_lds[el][col]);
            float kv = bf2f(k_lds[el][col]);
            float p = qv * (kv + acc[cf][r] + bev);
            p += __shfl_xor(p, 1);
            p += __shfl_xor(p, 2);
            p += __shfl_xor(p, 4);
            if ((lr & 7) == 0)
                ex_lds[el][cf * 2 + (lr >> 3)] = __expf(p * scale);  // shift-invariant softmax, no max pass
        }
    }

    __syncthreads();

    // coalesced ex store: 1KB contiguous per wave, slot-sequential
    int el = wave * 16 + (lane >> 2);
    float4 av = *(const float4*)(&ex_lds[el][(lane & 3) * 4]);
    *(float4*)(ex + (size_t)(s0 + el) * 16 + (lane & 3) * 4) = av;
}

// ---------------- aggregation: one wave per node; sequential ex, v-row gather only ----------------
__global__ void agg_kernel(const int* __restrict__ row_ptr, const int* __restrict__ src_ord,
                           const float* __restrict__ ex, const unsigned short* __restrict__ qkvs,
                           unsigned short* __restrict__ aggxr) {
    int w = (blockIdx.x * blockDim.x + threadIdx.x) >> 6;
    int lane = threadIdx.x & 63;
    if (w >= N_NODES) return;
    int c = lane * 2, h = lane >> 2;
    int s = row_ptr[w], e = row_ptr[w + 1], deg = e - s;
    int src_p = (lane < deg) ? src_ord[s + lane] : 0;
    float acc0 = 0.f, acc1 = 0.f, den = 0.f;
    for (int i = 0; i < deg; ++i) {
        int src = (i < 64) ? __shfl(src_p, i) : src_ord[s + i];
        float exv = ex[(size_t)(s + i) * H + h];
        ushort2 v2 = *(const ushort2*)(qkvs + (size_t)src * 512 + 256 + c);
        acc0 += exv * bf2f(v2.x);
        acc1 += exv * bf2f(v2.y);
        den += exv;
    }
    float inv = den > 0.f ? 1.0f / den : 0.f;
    ushort2 x2 = *(const ushort2*)(qkvs + (size_t)w * 512 + 384 + c);
    ushort2 o;
    o.x = f2bf(acc0 * inv + bf2f(x2.x));
    o.y = f2bf(acc1 * inv + bf2f(x2.y));
    *(ushort2*)(aggxr + (size_t)w * D + c) = o;
}

extern "C" void kernel_launch(void* const* d_in, const int* in_sizes, int n_in,
                              void* d_out, int out_size, void* d_ws, size_t ws_size,
                              hipStream_t stream) {
    const float* x = (const float*)d_in[0];
    const int* edge_index = (const int*)d_in[1];
    const float* edge_attr = (const float*)d_in[2];
    const float* ln1_g = (const float*)d_in[3];
    const float* ln1_b = (const float*)d_in[4];
    const float* wq = (const float*)d_in[5];  const float* bq = (const float*)d_in[6];
    const float* wk = (const float*)d_in[7];  const float* bk = (const float*)d_in[8];
    const float* wv = (const float*)d_in[9];  const float* bv = (const float*)d_in[10];
    const float* wsw = (const float*)d_in[11]; const float* bs = (const float*)d_in[12];
    const float* we = (const float*)d_in[13]; const float* be = (const float*)d_in[14];
    const float* wp = (const float*)d_in[15]; const float* bp = (const float*)d_in[16];
    const float* mlp_g = (const float*)d_in[17]; const float* mlp_b = (const float*)d_in[18];
    const float* w1 = (const float*)d_in[19]; const float* b1 = (const float*)d_in[20];
    const float* w2 = (const float*)d_in[21]; const float* b2 = (const float*)d_in[22];

    char* base = (char*)d_ws;
    size_t off = 0;
    auto alloc = [&](size_t bytes) -> char* {
        char* p = base + off;
        off = (off + bytes + 255) & ~(size_t)255;
        return p;
    };
    unsigned short* qkvs   = (unsigned short*)alloc((size_t)N_NODES * 512 * 2);  // q|k|v|xr bf16
    float* ex_buf          = (float*)alloc((size_t)N_EDGES * H * 4);
    unsigned short* h_bf   = (unsigned short*)alloc((size_t)N_NODES * D * 2);
    unsigned short* aggxr  = (unsigned short*)alloc((size_t)N_NODES * D * 2);
    float* outbuf          = (float*)alloc((size_t)N_NODES * D * 4);
    unsigned short* ln2_bf = (unsigned short*)alloc((size_t)N_NODES * D * 2);
    unsigned short* silu_bf= (unsigned short*)alloc((size_t)N_NODES * DH * 2);
    int* counts            = (int*)alloc((size_t)N_NODES * 4);
    int* row_ptr           = (int*)alloc((size_t)(N_NODES + 1) * 4);
    int* cursor            = (int*)alloc((size_t)N_NODES * 4);
    int* eord              = (int*)alloc((size_t)N_EDGES * 4);
    int* src_ord           = (int*)alloc((size_t)N_EDGES * 4);
    int* dst_ord           = (int*)alloc((size_t)N_EDGES * 4);
    unsigned short* wqkvsT = (unsigned short*)alloc(512 * 128 * 2);
    unsigned short* weT    = (unsigned short*)alloc(128 * 128 * 2);
    unsigned short* wpT    = (unsigned short*)alloc(128 * 128 * 2);
    unsigned short* w1T    = (unsigned short*)alloc(512 * 128 * 2);
    unsigned short* w2T    = (unsigned short*)alloc(128 * 512 * 2);
    float* bias_qkvs       = (float*)alloc(512 * 4);

    // ---- weight prep (single launch) ----
    prep_kernel<<<898, 256, 0, stream>>>(wq, wk, wv, wsw, we, wp, w1, w2, bq, bk, bv, bs,
                                         wqkvsT, weT, wpT, w1T, w2T, bias_qkvs);

    // ---- CSR by dst ----
    hipMemsetAsync(counts, 0, (size_t)N_NODES * 4, stream);
    hist_kernel<<<(N_EDGES + 255) / 256, 256, 0, stream>>>(edge_index, counts);
    scan_kernel<<<1, 1024, 0, stream>>>(counts, row_ptr, cursor);
    scatter_kernel<<<(N_EDGES + 255) / 256, 256, 0, stream>>>(edge_index, cursor, eord, src_ord, dst_ord);

    // ---- node pipeline ----
    ln_kernel<<<(N_NODES + 3) / 4, 256, 0, stream>>>(x, ln1_g, ln1_b, h_bf, N_NODES);

    dim3 g_node((N_NODES + 63) / 64, 8);
    gemm_kernel<128, EPI_BF16><<<g_node, 256, 0, stream>>>(h_bf, wqkvsT, bias_qkvs, qkvs, nullptr, N_NODES, 512);

    edge_score_kernel<<<N_EDGES / 64, 256, 0, stream>>>(edge_attr, weT, be, eord, src_ord, dst_ord, qkvs, ex_buf);

    agg_kernel<<<(N_NODES + 3) / 4, 256, 0, stream>>>(row_ptr, src_ord, ex_buf, qkvs, aggxr);

    dim3 g_out((N_NODES + 63) / 64, 2);
    gemm_kernel<128, EPI_RESID><<<g_out, 256, 0, stream>>>(aggxr, wpT, bp, outbuf, x, N_NODES, 128);

    ln_kernel<<<(N_NODES + 3) / 4, 256, 0, stream>>>(outbuf, mlp_g, mlp_b, ln2_bf, N_NODES);

    dim3 g_mlp1((N_NODES + 63) / 64, 8);
    gemm_kernel<128, EPI_SILU_BF><<<g_mlp1, 256, 0, stream>>>(ln2_bf, w1T, b1, silu_bf, nullptr, N_NODES, 512);

    dim3 g_mlp2((N_NODES + 63) / 64, 2);
    gemm_kernel<512, EPI_ADDOUT><<<g_mlp2, 256, 0, stream>>>(silu_bf, w2T, b2, (float*)d_out, outbuf, N_NODES, 128);
}

// Round 5
// 859.989 us; speedup vs baseline: 1.1331x; 1.0282x over previous
//
#include <hip/hip_runtime.h>

#define N_NODES 50000
#define N_EDGES 800000
#define D 128
#define H 16
#define DH 512

typedef __attribute__((ext_vector_type(8))) short short8;
typedef __attribute__((ext_vector_type(4))) float f32x4;

static __device__ __forceinline__ unsigned short f2bf(float f) {
    unsigned u = __float_as_uint(f);
    u += 0x7FFF + ((u >> 16) & 1);   // round-to-nearest-even
    return (unsigned short)(u >> 16);
}
static __device__ __forceinline__ float bf2f(unsigned short u) {
    return __uint_as_float(((unsigned)u) << 16);
}

// ---------------- LayerNorm (f32 in -> bf16 out), one wave per row ----------------
__global__ void ln_kernel(const float* __restrict__ x, const float* __restrict__ g,
                          const float* __restrict__ b, unsigned short* __restrict__ out, int n) {
    int w = (blockIdx.x * blockDim.x + threadIdx.x) >> 6;
    int lane = threadIdx.x & 63;
    if (w >= n) return;
    float2 v = *(const float2*)(x + (size_t)w * D + lane * 2);
    float s = v.x + v.y, ss = v.x * v.x + v.y * v.y;
#pragma unroll
    for (int off = 32; off; off >>= 1) { s += __shfl_xor(s, off); ss += __shfl_xor(ss, off); }
    float mean = s * (1.0f / D);
    float var = ss * (1.0f / D) - mean * mean;
    float rstd = rsqrtf(var + 1e-5f);
    float2 gv = *(const float2*)(g + lane * 2);
    float2 bv = *(const float2*)(b + lane * 2);
    ushort2 o;
    o.x = f2bf((v.x - mean) * rstd * gv.x + bv.x);
    o.y = f2bf((v.y - mean) * rstd * gv.y + bv.y);
    *(ushort2*)(out + (size_t)w * D + lane * 2) = o;
}

// ---------------- fused weight prep: all transposes + bias concat in ONE launch ----------------
__global__ void prep_kernel(const float* __restrict__ wq, const float* __restrict__ wk,
                            const float* __restrict__ wv, const float* __restrict__ ws,
                            const float* __restrict__ we, const float* __restrict__ wp,
                            const float* __restrict__ w1, const float* __restrict__ w2,
                            const float* __restrict__ bq, const float* __restrict__ bk,
                            const float* __restrict__ bv, const float* __restrict__ bs,
                            unsigned short* __restrict__ wqkvsT, unsigned short* __restrict__ weT,
                            unsigned short* __restrict__ wpT, unsigned short* __restrict__ w1T,
                            unsigned short* __restrict__ w2T, float* __restrict__ bias_qkvs) {
    int idx = blockIdx.x * blockDim.x + threadIdx.x;
    if (idx < 65536) {                       // wq|wk|wv|ws -> wqkvsT [512][128]
        int seg = idx >> 14, r = idx & 16383;
        const float* src = seg == 0 ? wq : seg == 1 ? wk : seg == 2 ? wv : ws;
        int o = r >> 7, i = r & 127;
        wqkvsT[idx] = f2bf(src[i * 128 + o]);
    } else if (idx < 81920) {                // weT [128][128]
        int r = idx - 65536; int o = r >> 7, i = r & 127;
        weT[r] = f2bf(we[i * 128 + o]);
    } else if (idx < 98304) {                // wpT [128][128]
        int r = idx - 81920; int o = r >> 7, i = r & 127;
        wpT[r] = f2bf(wp[i * 128 + o]);
    } else if (idx < 163840) {               // w1T [512][128], src w1 [128][512]
        int r = idx - 98304; int o = r >> 7, i = r & 127;
        w1T[r] = f2bf(w1[i * 512 + o]);
    } else if (idx < 229376) {               // w2T [128][512], src w2 [512][128]
        int r = idx - 163840; int o = r >> 9, i = r & 511;
        w2T[r] = f2bf(w2[i * 128 + o]);
    } else if (idx < 229888) {               // bias concat
        int r = idx - 229376;
        const float* p = r < 128 ? bq : r < 256 ? bk : r < 384 ? bv : bs;
        bias_qkvs[r] = p[r & 127];
    }
}

// ---------------- CSR build ----------------
__global__ void hist_kernel(const int* __restrict__ edge_index, int* __restrict__ counts) {
    int e = blockIdx.x * blockDim.x + threadIdx.x;
    if (e < N_EDGES) atomicAdd(&counts[edge_index[N_EDGES + e]], 1);
}

__global__ void scan_kernel(const int* __restrict__ counts, int* __restrict__ row_ptr,
                            int* __restrict__ cursor) {
    __shared__ int sums[1024];
    int tid = threadIdx.x;
    const int CHUNK = (N_NODES + 1023) / 1024;  // 49
    int base = tid * CHUNK;
    int local = 0;
    for (int i = 0; i < CHUNK; ++i) {
        int idx = base + i;
        if (idx < N_NODES) local += counts[idx];
    }
    sums[tid] = local;
    __syncthreads();
    for (int off = 1; off < 1024; off <<= 1) {
        int t = (tid >= off) ? sums[tid - off] : 0;
        __syncthreads();
        sums[tid] += t;
        __syncthreads();
    }
    int run = sums[tid] - local;
    for (int i = 0; i < CHUNK; ++i) {
        int idx = base + i;
        if (idx < N_NODES) {
            row_ptr[idx] = run;
            cursor[idx] = run;
            run += counts[idx];
        }
    }
    if (tid == 1023) row_ptr[N_NODES] = run;
}

// emits eord (slot->eid) and src_ord (slot->src) for the aggregation pass
__global__ void scatter_kernel(const int* __restrict__ edge_index, int* __restrict__ cursor,
                               int* __restrict__ eord, int* __restrict__ src_ord) {
    int e = blockIdx.x * blockDim.x + threadIdx.x;
    if (e < N_EDGES) {
        int dst = edge_index[N_EDGES + e];
        int pos = atomicAdd(&cursor[dst], 1);
        eord[pos] = e;
        src_ord[pos] = edge_index[e];
    }
}

// ---------------- generic bf16 MFMA GEMM ----------------
enum { EPI_F32 = 0, EPI_RESID = 1, EPI_SILU_BF = 2, EPI_ADDOUT = 3, EPI_BF16 = 4 };

template <int KD, int EPI>
__global__ void gemm_kernel(const unsigned short* __restrict__ A, const unsigned short* __restrict__ BT,
                            const float* __restrict__ bias, void* __restrict__ outp,
                            const float* __restrict__ extra, int M, int Nout) {
    int wave = threadIdx.x >> 6, lane = threadIdx.x & 63;
    int lr = lane & 15, lq = lane >> 4;
    int row0 = (blockIdx.x * 4 + wave) * 16;
    int col0 = blockIdx.y * 64;
    int arow = row0 + lr;
    if (arow >= M) arow = M - 1;
    f32x4 z = {0.f, 0.f, 0.f, 0.f};
    f32x4 acc[4] = {z, z, z, z};
#pragma unroll
    for (int t = 0; t < KD / 32; ++t) {
        short8 a = *(const short8*)(A + (size_t)arow * KD + t * 32 + lq * 8);
#pragma unroll
        for (int cf = 0; cf < 4; ++cf) {
            short8 b = *(const short8*)(BT + (size_t)(col0 + cf * 16 + lr) * KD + t * 32 + lq * 8);
            acc[cf] = __builtin_amdgcn_mfma_f32_16x16x32_bf16(a, b, acc[cf], 0, 0, 0);
        }
    }
#pragma unroll
    for (int cf = 0; cf < 4; ++cf) {
        int col = col0 + cf * 16 + lr;
        float bv = bias[col];
#pragma unroll
        for (int r = 0; r < 4; ++r) {
            int row = row0 + lq * 4 + r;
            if (row >= M) continue;
            float v = acc[cf][r] + bv;
            if (EPI == EPI_F32) {
                ((float*)outp)[(size_t)row * Nout + col] = v;
            } else if (EPI == EPI_RESID) {
                ((float*)outp)[(size_t)row * Nout + col] = v + extra[(size_t)row * D + col];
            } else if (EPI == EPI_SILU_BF) {
                float sg = 1.0f / (1.0f + __expf(-v));
                ((unsigned short*)outp)[(size_t)row * Nout + col] = f2bf(v * sg);
            } else if (EPI == EPI_ADDOUT) {
                ((float*)outp)[(size_t)row * Nout + col] = v + extra[(size_t)row * D + col];
            } else {  // EPI_BF16
                ((unsigned short*)outp)[(size_t)row * Nout + col] = f2bf(v);
            }
        }
    }
}

// ---------------- fused edge GEMM + full score + exp, SEQUENTIAL edge order ----------------
// edge_attr is a pure stream; q[dst]/k[src] rows gathered from 25.6MB bf16 region
// (L2/L3-served); ex written sequentially as bf16. No eord indirection anywhere.
__global__ void edge_score_kernel(const float* __restrict__ edge_attr,
                                  const unsigned short* __restrict__ weT,
                                  const float* __restrict__ be, const int* __restrict__ edge_index,
                                  const unsigned short* __restrict__ qkvs,
                                  unsigned short* __restrict__ ex16) {
    // stride 132 shorts (66 dw): score-read banks = 8*lq + lr/2 -> all 32 distinct
    __shared__ unsigned short qk_lds[2][64][132];
    __shared__ float ex_lds[64][20];  // stride 20 dw: worst 2-way (free)
    int wave = threadIdx.x >> 6, lane = threadIdx.x & 63;
    int lr = lane & 15, lq = lane >> 4;
    int e0 = blockIdx.x * 64;
    int e0w = e0 + wave * 16;
    int w16 = wave * 16;

    // coalesced index loads (one 64B segment each), broadcast later via shfl
    int srcv = edge_index[e0w + lr];
    int dstv = edge_index[N_EDGES + e0w + lr];

    // stage q[dst] (lanes 0-31) and k[src] (lanes 32-63): 256B per row, 16 independent loads
    int plane = lane >> 5, h2 = lane & 31;
#pragma unroll
    for (int it = 0; it < 16; ++it) {
        int dst = __shfl(dstv, it);
        int src = __shfl(srcv, it);
        int node = plane ? src : dst;
        const unsigned short* gp = qkvs + (size_t)node * 512 + plane * 128 + h2 * 4;
        *(ushort4*)(&qk_lds[plane][w16 + it][h2 * 4]) = *(const ushort4*)gp;
    }

    // A fragments: streaming read of 16 sequential edge_attr rows
    short8 a[4];
#pragma unroll
    for (int t = 0; t < 4; ++t) {
        const float* p = edge_attr + (size_t)(e0w + lr) * D + t * 32 + lq * 8;
        float4 lo = *(const float4*)p;
        float4 hi = *(const float4*)(p + 4);
        short8 av;
        av[0] = f2bf(lo.x); av[1] = f2bf(lo.y); av[2] = f2bf(lo.z); av[3] = f2bf(lo.w);
        av[4] = f2bf(hi.x); av[5] = f2bf(hi.y); av[6] = f2bf(hi.z); av[7] = f2bf(hi.w);
        a[t] = av;
    }
    f32x4 z = {0.f, 0.f, 0.f, 0.f};
    f32x4 acc[8] = {z, z, z, z, z, z, z, z};
#pragma unroll
    for (int cf = 0; cf < 8; ++cf) {
#pragma unroll
        for (int t = 0; t < 4; ++t) {
            short8 b = *(const short8*)(weT + (size_t)(cf * 16 + lr) * D + t * 32 + lq * 8);
            acc[cf] = __builtin_amdgcn_mfma_f32_16x16x32_bf16(a[t], b, acc[cf], 0, 0, 0);
        }
    }

    __syncthreads();

    const float scale = 0.35355339059327373f;  // 1/sqrt(8)
#pragma unroll
    for (int cf = 0; cf < 8; ++cf) {
        int col = cf * 16 + lr;
        float bev = be[col];
#pragma unroll
        for (int r = 0; r < 4; ++r) {
            int el = w16 + lq * 4 + r;
            float qv = bf2f(qk_lds[0][el][col]);
            float kv = bf2f(qk_lds[1][el][col]);
            float p = qv * (kv + acc[cf][r] + bev);
            p += __shfl_xor(p, 1);
            p += __shfl_xor(p, 2);
            p += __shfl_xor(p, 4);
            if ((lr & 7) == 0)
                ex_lds[el][cf * 2 + (lr >> 3)] = __expf(p * scale);  // shift-invariant softmax
        }
    }

    __syncthreads();

    // coalesced bf16 ex store: 512B contiguous per wave
    float4 av = *(const float4*)(&ex_lds[w16 + (lane >> 2)][(lane & 3) * 4]);
    ushort4 o;
    o.x = f2bf(av.x); o.y = f2bf(av.y); o.z = f2bf(av.z); o.w = f2bf(av.w);
    *(ushort4*)(ex16 + (size_t)e0w * 16 + lane * 4) = o;
}

// ---------------- aggregation: one wave per node; ex gathered from L3-resident bf16 buffer ----------------
__global__ void agg_kernel(const int* __restrict__ row_ptr, const int* __restrict__ eord,
                           const int* __restrict__ src_ord, const unsigned short* __restrict__ ex16,
                           const unsigned short* __restrict__ qkvs, unsigned short* __restrict__ aggxr) {
    int w = (blockIdx.x * blockDim.x + threadIdx.x) >> 6;
    int lane = threadIdx.x & 63;
    if (w >= N_NODES) return;
    int c = lane * 2, h = lane >> 2;
    int s = row_ptr[w], e = row_ptr[w + 1], deg = e - s;
    int src_p = 0, eid_p = 0;
    if (lane < deg) { src_p = src_ord[s + lane]; eid_p = eord[s + lane]; }
    float acc0 = 0.f, acc1 = 0.f, den = 0.f;
    for (int i = 0; i < deg; ++i) {
        int src, eid;
        if (i < 64) { src = __shfl(src_p, i); eid = __shfl(eid_p, i); }
        else { src = src_ord[s + i]; eid = eord[s + i]; }
        float exv = bf2f(ex16[(size_t)eid * H + h]);
        ushort2 v2 = *(const ushort2*)(qkvs + (size_t)src * 512 + 256 + c);
        acc0 += exv * bf2f(v2.x);
        acc1 += exv * bf2f(v2.y);
        den += exv;
    }
    float inv = den > 0.f ? 1.0f / den : 0.f;
    ushort2 x2 = *(const ushort2*)(qkvs + (size_t)w * 512 + 384 + c);
    ushort2 o;
    o.x = f2bf(acc0 * inv + bf2f(x2.x));
    o.y = f2bf(acc1 * inv + bf2f(x2.y));
    *(ushort2*)(aggxr + (size_t)w * D + c) = o;
}

extern "C" void kernel_launch(void* const* d_in, const int* in_sizes, int n_in,
                              void* d_out, int out_size, void* d_ws, size_t ws_size,
                              hipStream_t stream) {
    const float* x = (const float*)d_in[0];
    const int* edge_index = (const int*)d_in[1];
    const float* edge_attr = (const float*)d_in[2];
    const float* ln1_g = (const float*)d_in[3];
    const float* ln1_b = (const float*)d_in[4];
    const float* wq = (const float*)d_in[5];  const float* bq = (const float*)d_in[6];
    const float* wk = (const float*)d_in[7];  const float* bk = (const float*)d_in[8];
    const float* wv = (const float*)d_in[9];  const float* bv = (const float*)d_in[10];
    const float* wsw = (const float*)d_in[11]; const float* bs = (const float*)d_in[12];
    const float* we = (const float*)d_in[13]; const float* be = (const float*)d_in[14];
    const float* wp = (const float*)d_in[15]; const float* bp = (const float*)d_in[16];
    const float* mlp_g = (const float*)d_in[17]; const float* mlp_b = (const float*)d_in[18];
    const float* w1 = (const float*)d_in[19]; const float* b1 = (const float*)d_in[20];
    const float* w2 = (const float*)d_in[21]; const float* b2 = (const float*)d_in[22];

    char* base = (char*)d_ws;
    size_t off = 0;
    auto alloc = [&](size_t bytes) -> char* {
        char* p = base + off;
        off = (off + bytes + 255) & ~(size_t)255;
        return p;
    };
    unsigned short* qkvs   = (unsigned short*)alloc((size_t)N_NODES * 512 * 2);  // q|k|v|xr bf16
    unsigned short* ex16   = (unsigned short*)alloc((size_t)N_EDGES * H * 2);
    unsigned short* h_bf   = (unsigned short*)alloc((size_t)N_NODES * D * 2);
    unsigned short* aggxr  = (unsigned short*)alloc((size_t)N_NODES * D * 2);
    float* outbuf          = (float*)alloc((size_t)N_NODES * D * 4);
    unsigned short* ln2_bf = (unsigned short*)alloc((size_t)N_NODES * D * 2);
    unsigned short* silu_bf= (unsigned short*)alloc((size_t)N_NODES * DH * 2);
    int* counts            = (int*)alloc((size_t)N_NODES * 4);
    int* row_ptr           = (int*)alloc((size_t)(N_NODES + 1) * 4);
    int* cursor            = (int*)alloc((size_t)N_NODES * 4);
    int* eord              = (int*)alloc((size_t)N_EDGES * 4);
    int* src_ord           = (int*)alloc((size_t)N_EDGES * 4);
    unsigned short* wqkvsT = (unsigned short*)alloc(512 * 128 * 2);
    unsigned short* weT    = (unsigned short*)alloc(128 * 128 * 2);
    unsigned short* wpT    = (unsigned short*)alloc(128 * 128 * 2);
    unsigned short* w1T    = (unsigned short*)alloc(512 * 128 * 2);
    unsigned short* w2T    = (unsigned short*)alloc(128 * 512 * 2);
    float* bias_qkvs       = (float*)alloc(512 * 4);

    // ---- weight prep (single launch) ----
    prep_kernel<<<898, 256, 0, stream>>>(wq, wk, wv, wsw, we, wp, w1, w2, bq, bk, bv, bs,
                                         wqkvsT, weT, wpT, w1T, w2T, bias_qkvs);

    // ---- CSR by dst ----
    hipMemsetAsync(counts, 0, (size_t)N_NODES * 4, stream);
    hist_kernel<<<(N_EDGES + 255) / 256, 256, 0, stream>>>(edge_index, counts);
    scan_kernel<<<1, 1024, 0, stream>>>(counts, row_ptr, cursor);
    scatter_kernel<<<(N_EDGES + 255) / 256, 256, 0, stream>>>(edge_index, cursor, eord, src_ord);

    // ---- node pipeline ----
    ln_kernel<<<(N_NODES + 3) / 4, 256, 0, stream>>>(x, ln1_g, ln1_b, h_bf, N_NODES);

    dim3 g_node((N_NODES + 63) / 64, 8);
    gemm_kernel<128, EPI_BF16><<<g_node, 256, 0, stream>>>(h_bf, wqkvsT, bias_qkvs, qkvs, nullptr, N_NODES, 512);

    edge_score_kernel<<<N_EDGES / 64, 256, 0, stream>>>(edge_attr, weT, be, edge_index, qkvs, ex16);

    agg_kernel<<<(N_NODES + 3) / 4, 256, 0, stream>>>(row_ptr, eord, src_ord, ex16, qkvs, aggxr);

    dim3 g_out((N_NODES + 63) / 64, 2);
    gemm_kernel<128, EPI_RESID><<<g_out, 256, 0, stream>>>(aggxr, wpT, bp, outbuf, x, N_NODES, 128);

    ln_kernel<<<(N_NODES + 3) / 4, 256, 0, stream>>>(outbuf, mlp_g, mlp_b, ln2_bf, N_NODES);

    dim3 g_mlp1((N_NODES + 63) / 64, 8);
    gemm_kernel<128, EPI_SILU_BF><<<g_mlp1, 256, 0, stream>>>(ln2_bf, w1T, b1, silu_bf, nullptr, N_NODES, 512);

    dim3 g_mlp2((N_NODES + 63) / 64, 2);
    gemm_kernel<512, EPI_ADDOUT><<<g_mlp2, 256, 0, stream>>>(silu_bf, w2T, b2, (float*)d_out, outbuf, N_NODES, 128);
}

// Round 7
// 836.952 us; speedup vs baseline: 1.1643x; 1.0275x over previous
//
#include <hip/hip_runtime.h>

#define N_NODES 50000
#define N_EDGES 800000
#define D 128
#define H 16
#define DH 512

typedef __attribute__((ext_vector_type(8))) short short8;
typedef __attribute__((ext_vector_type(4))) float f32x4;

static __device__ __forceinline__ unsigned short f2bf(float f) {
    unsigned u = __float_as_uint(f);
    u += 0x7FFF + ((u >> 16) & 1);   // round-to-nearest-even
    return (unsigned short)(u >> 16);
}
static __device__ __forceinline__ float bf2f(unsigned short u) {
    return __uint_as_float(((unsigned)u) << 16);
}

// ---------------- LayerNorm (f32 in -> bf16 out), one wave per row ----------------
__global__ void ln_kernel(const float* __restrict__ x, const float* __restrict__ g,
                          const float* __restrict__ b, unsigned short* __restrict__ out, int n) {
    int w = (blockIdx.x * blockDim.x + threadIdx.x) >> 6;
    int lane = threadIdx.x & 63;
    if (w >= n) return;
    float2 v = *(const float2*)(x + (size_t)w * D + lane * 2);
    float s = v.x + v.y, ss = v.x * v.x + v.y * v.y;
#pragma unroll
    for (int off = 32; off; off >>= 1) { s += __shfl_xor(s, off); ss += __shfl_xor(ss, off); }
    float mean = s * (1.0f / D);
    float var = ss * (1.0f / D) - mean * mean;
    float rstd = rsqrtf(var + 1e-5f);
    float2 gv = *(const float2*)(g + lane * 2);
    float2 bv = *(const float2*)(b + lane * 2);
    ushort2 o;
    o.x = f2bf((v.x - mean) * rstd * gv.x + bv.x);
    o.y = f2bf((v.y - mean) * rstd * gv.y + bv.y);
    *(ushort2*)(out + (size_t)w * D + lane * 2) = o;
}

// ---------------- fused weight prep: all transposes + bias concat in ONE launch ----------------
__global__ void prep_kernel(const float* __restrict__ wq, const float* __restrict__ wk,
                            const float* __restrict__ wv, const float* __restrict__ ws,
                            const float* __restrict__ we, const float* __restrict__ wp,
                            const float* __restrict__ w1, const float* __restrict__ w2,
                            const float* __restrict__ bq, const float* __restrict__ bk,
                            const float* __restrict__ bv, const float* __restrict__ bs,
                            unsigned short* __restrict__ wqkvsT, unsigned short* __restrict__ weT,
                            unsigned short* __restrict__ wpT, unsigned short* __restrict__ w1T,
                            unsigned short* __restrict__ w2T, float* __restrict__ bias_qkvs) {
    int idx = blockIdx.x * blockDim.x + threadIdx.x;
    if (idx < 65536) {                       // wq|wk|wv|ws -> wqkvsT [512][128]
        int seg = idx >> 14, r = idx & 16383;
        const float* src = seg == 0 ? wq : seg == 1 ? wk : seg == 2 ? wv : ws;
        int o = r >> 7, i = r & 127;
        wqkvsT[idx] = f2bf(src[i * 128 + o]);
    } else if (idx < 81920) {                // weT [128][128]
        int r = idx - 65536; int o = r >> 7, i = r & 127;
        weT[r] = f2bf(we[i * 128 + o]);
    } else if (idx < 98304) {                // wpT [128][128]
        int r = idx - 81920; int o = r >> 7, i = r & 127;
        wpT[r] = f2bf(wp[i * 128 + o]);
    } else if (idx < 163840) {               // w1T [512][128], src w1 [128][512]
        int r = idx - 98304; int o = r >> 7, i = r & 127;
        w1T[r] = f2bf(w1[i * 512 + o]);
    } else if (idx < 229376) {               // w2T [128][512], src w2 [512][128]
        int r = idx - 163840; int o = r >> 9, i = r & 511;
        w2T[r] = f2bf(w2[i * 128 + o]);
    } else if (idx < 229888) {               // bias concat
        int r = idx - 229376;
        const float* p = r < 128 ? bq : r < 256 ? bk : r < 384 ? bv : bs;
        bias_qkvs[r] = p[r & 127];
    }
}

// ---------------- CSR build ----------------
__global__ void hist_kernel(const int* __restrict__ edge_index, int* __restrict__ counts) {
    int e = blockIdx.x * blockDim.x + threadIdx.x;
    if (e < N_EDGES) atomicAdd(&counts[edge_index[N_EDGES + e]], 1);
}

__global__ void scan_kernel(const int* __restrict__ counts, int* __restrict__ row_ptr,
                            int* __restrict__ cursor) {
    __shared__ int sums[1024];
    int tid = threadIdx.x;
    const int CHUNK = (N_NODES + 1023) / 1024;  // 49
    int base = tid * CHUNK;
    int local = 0;
    for (int i = 0; i < CHUNK; ++i) {
        int idx = base + i;
        if (idx < N_NODES) local += counts[idx];
    }
    sums[tid] = local;
    __syncthreads();
    for (int off = 1; off < 1024; off <<= 1) {
        int t = (tid >= off) ? sums[tid - off] : 0;
        __syncthreads();
        sums[tid] += t;
        __syncthreads();
    }
    int run = sums[tid] - local;
    for (int i = 0; i < CHUNK; ++i) {
        int idx = base + i;
        if (idx < N_NODES) {
            row_ptr[idx] = run;
            cursor[idx] = run;
            run += counts[idx];
        }
    }
    if (tid == 1023) row_ptr[N_NODES] = run;
}

// emits slot_of (edge -> CSR slot) and src_ord (slot -> src node)
__global__ void scatter_kernel(const int* __restrict__ edge_index, int* __restrict__ cursor,
                               int* __restrict__ slot_of, int* __restrict__ src_ord) {
    int e = blockIdx.x * blockDim.x + threadIdx.x;
    if (e < N_EDGES) {
        int dst = edge_index[N_EDGES + e];
        int pos = atomicAdd(&cursor[dst], 1);
        slot_of[e] = pos;
        src_ord[pos] = edge_index[e];
    }
}

// ---------------- generic bf16 MFMA GEMM ----------------
enum { EPI_F32 = 0, EPI_RESID = 1, EPI_SILU_BF = 2, EPI_ADDOUT = 3, EPI_BF16 = 4 };

template <int KD, int EPI>
__global__ void gemm_kernel(const unsigned short* __restrict__ A, const unsigned short* __restrict__ BT,
                            const float* __restrict__ bias, void* __restrict__ outp,
                            const float* __restrict__ extra, int M, int Nout) {
    int wave = threadIdx.x >> 6, lane = threadIdx.x & 63;
    int lr = lane & 15, lq = lane >> 4;
    int row0 = (blockIdx.x * 4 + wave) * 16;
    int col0 = blockIdx.y * 64;
    int arow = row0 + lr;
    if (arow >= M) arow = M - 1;
    f32x4 z = {0.f, 0.f, 0.f, 0.f};
    f32x4 acc[4] = {z, z, z, z};
#pragma unroll
    for (int t = 0; t < KD / 32; ++t) {
        short8 a = *(const short8*)(A + (size_t)arow * KD + t * 32 + lq * 8);
#pragma unroll
        for (int cf = 0; cf < 4; ++cf) {
            short8 b = *(const short8*)(BT + (size_t)(col0 + cf * 16 + lr) * KD + t * 32 + lq * 8);
            acc[cf] = __builtin_amdgcn_mfma_f32_16x16x32_bf16(a, b, acc[cf], 0, 0, 0);
        }
    }
#pragma unroll
    for (int cf = 0; cf < 4; ++cf) {
        int col = col0 + cf * 16 + lr;
        float bv = bias[col];
#pragma unroll
        for (int r = 0; r < 4; ++r) {
            int row = row0 + lq * 4 + r;
            if (row >= M) continue;
            float v = acc[cf][r] + bv;
            if (EPI == EPI_F32) {
                ((float*)outp)[(size_t)row * Nout + col] = v;
            } else if (EPI == EPI_RESID) {
                ((float*)outp)[(size_t)row * Nout + col] = v + extra[(size_t)row * D + col];
            } else if (EPI == EPI_SILU_BF) {
                float sg = 1.0f / (1.0f + __expf(-v));
                ((unsigned short*)outp)[(size_t)row * Nout + col] = f2bf(v * sg);
            } else if (EPI == EPI_ADDOUT) {
                ((float*)outp)[(size_t)row * Nout + col] = v + extra[(size_t)row * D + col];
            } else {  // EPI_BF16
                ((unsigned short*)outp)[(size_t)row * Nout + col] = f2bf(v);
            }
        }
    }
}

// ---------------- fused edge GEMM + q.(E+be) partial score, SEQUENTIAL edge order ----------------
// Only q rows gathered (205MB logical, L2/L3-served). qE stored f32 directly in CSR
// slot order (64B scattered stores) so agg reads scores sequentially. q.k moved to agg.
__global__ void edge_score_kernel(const float* __restrict__ edge_attr,
                                  const unsigned short* __restrict__ weT,
                                  const float* __restrict__ be, const int* __restrict__ edge_index,
                                  const int* __restrict__ slot_of,
                                  const unsigned short* __restrict__ qkvs,
                                  float* __restrict__ qE) {
    __shared__ unsigned short q_lds[64][132];  // stride 66 dw: score-read banks 8*lq+2r+8cf+lr/2 -> 32 distinct
    __shared__ float s_lds[64][20];            // stride 20 dw: worst 2-way (free)
    int wave = threadIdx.x >> 6, lane = threadIdx.x & 63;
    int lr = lane & 15, lq = lane >> 4;
    int e0w = blockIdx.x * 64 + wave * 16;
    int w16 = wave * 16;

    // coalesced index loads, broadcast via shfl
    int dstv = edge_index[N_EDGES + e0w + lr];
    int slotv = slot_of[e0w + lr];

    // stage q[dst] rows: 2 rows per iteration (half-wave each, 256B coalesced)
    int plane = lane >> 5, h2 = lane & 31;
#pragma unroll
    for (int it = 0; it < 8; ++it) {
        int row16 = it * 2 + plane;
        int dst = __shfl(dstv, row16);
        *(ushort4*)(&q_lds[w16 + row16][h2 * 4]) =
            *(const ushort4*)(qkvs + (size_t)dst * 512 + h2 * 4);
    }

    // A fragments: nontemporal streaming read of 16 sequential edge_attr rows
    short8 a[4];
#pragma unroll
    for (int t = 0; t < 4; ++t) {
        const f32x4* p = (const f32x4*)(edge_attr + (size_t)(e0w + lr) * D + t * 32 + lq * 8);
        f32x4 lo = __builtin_nontemporal_load(p);
        f32x4 hi = __builtin_nontemporal_load(p + 1);
        short8 av;
        av[0] = f2bf(lo[0]); av[1] = f2bf(lo[1]); av[2] = f2bf(lo[2]); av[3] = f2bf(lo[3]);
        av[4] = f2bf(hi[0]); av[5] = f2bf(hi[1]); av[6] = f2bf(hi[2]); av[7] = f2bf(hi[3]);
        a[t] = av;
    }
    f32x4 z = {0.f, 0.f, 0.f, 0.f};
    f32x4 acc[8] = {z, z, z, z, z, z, z, z};
#pragma unroll
    for (int cf = 0; cf < 8; ++cf) {
#pragma unroll
        for (int t = 0; t < 4; ++t) {
            short8 b = *(const short8*)(weT + (size_t)(cf * 16 + lr) * D + t * 32 + lq * 8);
            acc[cf] = __builtin_amdgcn_mfma_f32_16x16x32_bf16(a[t], b, acc[cf], 0, 0, 0);
        }
    }

    __syncthreads();

    // partial score: qE[e][h] = sum_c q[dst][h][c] * (E[h][c] + be)   (unscaled, pre-exp)
#pragma unroll
    for (int cf = 0; cf < 8; ++cf) {
        int col = cf * 16 + lr;
        float bev = be[col];
#pragma unroll
        for (int r = 0; r < 4; ++r) {
            int el = w16 + lq * 4 + r;
            float qv = bf2f(q_lds[el][col]);
            float p = qv * (acc[cf][r] + bev);
            p += __shfl_xor(p, 1);
            p += __shfl_xor(p, 2);
            p += __shfl_xor(p, 4);
            if ((lr & 7) == 0)
                s_lds[el][cf * 2 + (lr >> 3)] = p;
        }
    }

    __syncthreads();

    // CSR-slot-ordered store: 4 lanes per edge, one float4 each (64B per edge)
    int el16 = lane >> 2;
    int slot = __shfl(slotv, el16);
    f32x4 sv = *(const f32x4*)(&s_lds[w16 + el16][(lane & 3) * 4]);
    *(f32x4*)(qE + (size_t)slot * 16 + (lane & 3) * 4) = sv;
}

// ---------------- aggregation: one wave per node; q.k computed here (q loop-invariant) ----------------
__global__ void agg_kernel(const int* __restrict__ row_ptr, const int* __restrict__ src_ord,
                           const float* __restrict__ qE, const unsigned short* __restrict__ qkvs,
                           unsigned short* __restrict__ aggxr) {
    int w = (blockIdx.x * blockDim.x + threadIdx.x) >> 6;
    int lane = threadIdx.x & 63;
    if (w >= N_NODES) return;
    int c = lane * 2, h = lane >> 2;
    int s = row_ptr[w], e = row_ptr[w + 1], deg = e - s;
    int src_p = (lane < deg) ? src_ord[s + lane] : 0;
    ushort2 q2 = *(const ushort2*)(qkvs + (size_t)w * 512 + c);
    float qa = bf2f(q2.x), qb = bf2f(q2.y);
    const float scale = 0.35355339059327373f;  // 1/sqrt(8)
    float acc0 = 0.f, acc1 = 0.f, den = 0.f;
    for (int i = 0; i < deg; ++i) {
        int src = (i < 64) ? __shfl(src_p, i) : src_ord[s + i];
        ushort2 k2 = *(const ushort2*)(qkvs + (size_t)src * 512 + 128 + c);
        ushort2 v2 = *(const ushort2*)(qkvs + (size_t)src * 512 + 256 + c);
        float pa = qa * bf2f(k2.x) + qb * bf2f(k2.y);
        pa += __shfl_xor(pa, 1);
        pa += __shfl_xor(pa, 2);
        float qEv = qE[(size_t)(s + i) * 16 + h];   // sequential 64B segment per edge
        float ex = __expf((pa + qEv) * scale);      // shift-invariant softmax, no max pass
        acc0 += ex * bf2f(v2.x);
        acc1 += ex * bf2f(v2.y);
        den += ex;
    }
    float inv = den > 0.f ? 1.0f / den : 0.f;
    ushort2 x2 = *(const ushort2*)(qkvs + (size_t)w * 512 + 384 + c);
    ushort2 o;
    o.x = f2bf(acc0 * inv + bf2f(x2.x));
    o.y = f2bf(acc1 * inv + bf2f(x2.y));
    *(ushort2*)(aggxr + (size_t)w * D + c) = o;
}

extern "C" void kernel_launch(void* const* d_in, const int* in_sizes, int n_in,
                              void* d_out, int out_size, void* d_ws, size_t ws_size,
                              hipStream_t stream) {
    const float* x = (const float*)d_in[0];
    const int* edge_index = (const int*)d_in[1];
    const float* edge_attr = (const float*)d_in[2];
    const float* ln1_g = (const float*)d_in[3];
    const float* ln1_b = (const float*)d_in[4];
    const float* wq = (const float*)d_in[5];  const float* bq = (const float*)d_in[6];
    const float* wk = (const float*)d_in[7];  const float* bk = (const float*)d_in[8];
    const float* wv = (const float*)d_in[9];  const float* bv = (const float*)d_in[10];
    const float* wsw = (const float*)d_in[11]; const float* bs = (const float*)d_in[12];
    const float* we = (const float*)d_in[13]; const float* be = (const float*)d_in[14];
    const float* wp = (const float*)d_in[15]; const float* bp = (const float*)d_in[16];
    const float* mlp_g = (const float*)d_in[17]; const float* mlp_b = (const float*)d_in[18];
    const float* w1 = (const float*)d_in[19]; const float* b1 = (const float*)d_in[20];
    const float* w2 = (const float*)d_in[21]; const float* b2 = (const float*)d_in[22];

    char* base = (char*)d_ws;
    size_t off = 0;
    auto alloc = [&](size_t bytes) -> char* {
        char* p = base + off;
        off = (off + bytes + 255) & ~(size_t)255;
        return p;
    };
    unsigned short* qkvs   = (unsigned short*)alloc((size_t)N_NODES * 512 * 2);  // q|k|v|xr bf16
    float* qE_buf          = (float*)alloc((size_t)N_EDGES * H * 4);
    unsigned short* h_bf   = (unsigned short*)alloc((size_t)N_NODES * D * 2);
    unsigned short* aggxr  = (unsigned short*)alloc((size_t)N_NODES * D * 2);
    float* outbuf          = (float*)alloc((size_t)N_NODES * D * 4);
    unsigned short* ln2_bf = (unsigned short*)alloc((size_t)N_NODES * D * 2);
    unsigned short* silu_bf= (unsigned short*)alloc((size_t)N_NODES * DH * 2);
    int* counts            = (int*)alloc((size_t)N_NODES * 4);
    int* row_ptr           = (int*)alloc((size_t)(N_NODES + 1) * 4);
    int* cursor            = (int*)alloc((size_t)N_NODES * 4);
    int* slot_of           = (int*)alloc((size_t)N_EDGES * 4);
    int* src_ord           = (int*)alloc((size_t)N_EDGES * 4);
    unsigned short* wqkvsT = (unsigned short*)alloc(512 * 128 * 2);
    unsigned short* weT    = (unsigned short*)alloc(128 * 128 * 2);
    unsigned short* wpT    = (unsigned short*)alloc(128 * 128 * 2);
    unsigned short* w1T    = (unsigned short*)alloc(512 * 128 * 2);
    unsigned short* w2T    = (unsigned short*)alloc(128 * 512 * 2);
    float* bias_qkvs       = (float*)alloc(512 * 4);

    // ---- weight prep (single launch) ----
    prep_kernel<<<898, 256, 0, stream>>>(wq, wk, wv, wsw, we, wp, w1, w2, bq, bk, bv, bs,
                                         wqkvsT, weT, wpT, w1T, w2T, bias_qkvs);

    // ---- CSR by dst ----
    (void)hipMemsetAsync(counts, 0, (size_t)N_NODES * 4, stream);
    hist_kernel<<<(N_EDGES + 255) / 256, 256, 0, stream>>>(edge_index, counts);
    scan_kernel<<<1, 1024, 0, stream>>>(counts, row_ptr, cursor);
    scatter_kernel<<<(N_EDGES + 255) / 256, 256, 0, stream>>>(edge_index, cursor, slot_of, src_ord);

    // ---- node pipeline ----
    ln_kernel<<<(N_NODES + 3) / 4, 256, 0, stream>>>(x, ln1_g, ln1_b, h_bf, N_NODES);

    dim3 g_node((N_NODES + 63) / 64, 8);
    gemm_kernel<128, EPI_BF16><<<g_node, 256, 0, stream>>>(h_bf, wqkvsT, bias_qkvs, qkvs, nullptr, N_NODES, 512);

    edge_score_kernel<<<N_EDGES / 64, 256, 0, stream>>>(edge_attr, weT, be, edge_index, slot_of, qkvs, qE_buf);

    agg_kernel<<<(N_NODES + 3) / 4, 256, 0, stream>>>(row_ptr, src_ord, qE_buf, qkvs, aggxr);

    dim3 g_out((N_NODES + 63) / 64, 2);
    gemm_kernel<128, EPI_RESID><<<g_out, 256, 0, stream>>>(aggxr, wpT, bp, outbuf, x, N_NODES, 128);

    ln_kernel<<<(N_NODES + 3) / 4, 256, 0, stream>>>(outbuf, mlp_g, mlp_b, ln2_bf, N_NODES);

    dim3 g_mlp1((N_NODES + 63) / 64, 8);
    gemm_kernel<128, EPI_SILU_BF><<<g_mlp1, 256, 0, stream>>>(ln2_bf, w1T, b1, silu_bf, nullptr, N_NODES, 512);

    dim3 g_mlp2((N_NODES + 63) / 64, 2);
    gemm_kernel<512, EPI_ADDOUT><<<g_mlp2, 256, 0, stream>>>(silu_bf, w2T, b2, (float*)d_out, outbuf, N_NODES, 128);
}